// Round 2
// baseline (564.253 us; speedup 1.0000x reference)
//
#include <hip/hip_runtime.h>
#include <hip/hip_bf16.h>
#include <math.h>

// ---------------------------------------------------------------------------
// AudioVQMix: wave VQ (1024 codes, D=80) + mfcc transform (cos-matmul 80->38,
// l2norm; the pre-norm cancels) + mfcc VQ (256 codes, D=38) + losses + ppl.
// Codebook / cos-table reads are wave-uniform -> forced onto the scalar
// (SMEM/SGPR) path via readfirstlane; no LDS in the inner loops.
// Output (float32): [0..131071] encodings, then wave_ppl, wave_loss,
// mfcc_ppl, mfcc_loss.
// ---------------------------------------------------------------------------

#define NROWS 65536        // 16 * 4096
#define DW    80
#define KW    1024
#define DM    38
#define DMP   40           // cos table padded (cols 38,39 = 0)
#define KM    256

// workspace layout (bytes)
//   0     : counts_w (1024 i32)
//   4096  : counts_m (256 i32)
//   5120  : sums (2 f32)
//   5632  : cn_w (1024 f32)
//   9728  : cn_m (256 f32)
//   10752 : costab (80*40 f32)

__global__ __launch_bounds__(256) void prep_kernel(
    const float* __restrict__ cbw, const float* __restrict__ cbm,
    int* __restrict__ counts_w, int* __restrict__ counts_m,
    float* __restrict__ sums, float* __restrict__ cn_w,
    float* __restrict__ cn_m, float* __restrict__ costab)
{
    int idx = blockIdx.x * 256 + threadIdx.x;
    if (idx < KW) {
        counts_w[idx] = 0;
        const float* p = cbw + (size_t)idx * DW;
        float s = 0.f;
        for (int i = 0; i < DW; ++i) s = fmaf(p[i], p[i], s);
        cn_w[idx] = s;
    } else if (idx < KW + KM) {
        int i = idx - KW;
        counts_m[i] = 0;
        const float* p = cbm + (size_t)i * DM;
        float s = 0.f;
        for (int j = 0; j < DM; ++j) s = fmaf(p[j], p[j], s);
        cn_m[i] = s;
    } else if (idx < KW + KM + DW * DMP) {
        int t = idx - (KW + KM);
        int d = t / DMP, j = t % DMP;
        double v = (j < DM)
            ? cos(2.0 * 3.14159265358979323846 * (double)((j + 2) * d) / 80.0)
            : 0.0;
        costab[t] = (float)v;
    } else if (idx == KW + KM + DW * DMP)     sums[0] = 0.f;
    else if (idx == KW + KM + DW * DMP + 1)   sums[1] = 0.f;
}

// Wave VQ: 64 rows/block, 4 threads/row; thread q scans codes
// [q*256, q*256+256). Code rows read with wave-uniform addresses -> SGPRs.
__global__ __launch_bounds__(256, 4) void wave_vq_kernel(
    const float* __restrict__ X, const float* __restrict__ cb,
    const float* __restrict__ cn, float* __restrict__ out,
    int* __restrict__ counts, float* __restrict__ loss_sum)
{
    __shared__ float red_d[256];
    __shared__ int   red_i[256];

    const int tid = threadIdx.x;
    const int rl  = tid & 63;
    const int qu  = __builtin_amdgcn_readfirstlane(tid >> 6);  // wave-uniform
    const size_t r = (size_t)blockIdx.x * 64 + rl;

    float x[DW];
    const float4* xp = (const float4*)(X + r * DW);
    #pragma unroll
    for (int i = 0; i < DW / 4; ++i) {
        float4 v = xp[i];
        x[4*i+0] = v.x; x[4*i+1] = v.y; x[4*i+2] = v.z; x[4*i+3] = v.w;
    }

    const int cbase = qu * (KW / 4);
    float best = 3.4e38f; int bidx = cbase;

    for (int c = 0; c < KW / 4; ++c) {
        const float4* cr4 = (const float4*)(cb + (size_t)(cbase + c) * DW);
        float a0 = 0.f, a1 = 0.f, a2 = 0.f, a3 = 0.f;
        #pragma unroll
        for (int k = 0; k < 5; ++k) {
            float4 v0 = cr4[4*k+0];
            float4 v1 = cr4[4*k+1];
            float4 v2 = cr4[4*k+2];
            float4 v3 = cr4[4*k+3];
            a0 = fmaf(x[16*k+ 0], v0.x, a0); a0 = fmaf(x[16*k+ 1], v0.y, a0);
            a0 = fmaf(x[16*k+ 2], v0.z, a0); a0 = fmaf(x[16*k+ 3], v0.w, a0);
            a1 = fmaf(x[16*k+ 4], v1.x, a1); a1 = fmaf(x[16*k+ 5], v1.y, a1);
            a1 = fmaf(x[16*k+ 6], v1.z, a1); a1 = fmaf(x[16*k+ 7], v1.w, a1);
            a2 = fmaf(x[16*k+ 8], v2.x, a2); a2 = fmaf(x[16*k+ 9], v2.y, a2);
            a2 = fmaf(x[16*k+10], v2.z, a2); a2 = fmaf(x[16*k+11], v2.w, a2);
            a3 = fmaf(x[16*k+12], v3.x, a3); a3 = fmaf(x[16*k+13], v3.y, a3);
            a3 = fmaf(x[16*k+14], v3.z, a3); a3 = fmaf(x[16*k+15], v3.w, a3);
        }
        float d = cn[cbase + c] - 2.0f * ((a0 + a1) + (a2 + a3));
        if (d < best) { best = d; bidx = cbase + c; }
    }

    red_d[tid] = best; red_i[tid] = bidx;
    __syncthreads();
    if (tid < 64) {
        #pragma unroll
        for (int qq = 1; qq < 4; ++qq) {
            float d2 = red_d[qq * 64 + tid];
            int   i2 = red_i[qq * 64 + tid];
            if (d2 < best || (d2 == best && i2 < bidx)) { best = d2; bidx = i2; }
        }
        out[2 * r] = (float)bidx;
        atomicAdd(&counts[bidx], 1);
        const float4* qp = (const float4*)(cb + (size_t)bidx * DW);
        float s = 0.f;
        #pragma unroll
        for (int i = 0; i < DW / 4; ++i) {
            float4 v = qp[i];
            float d0 = x[4*i+0] - v.x, d1 = x[4*i+1] - v.y;
            float d2 = x[4*i+2] - v.z, d3 = x[4*i+3] - v.w;
            s = fmaf(d0, d0, s); s = fmaf(d1, d1, s);
            s = fmaf(d2, d2, s); s = fmaf(d3, d3, s);
        }
        #pragma unroll
        for (int off = 32; off >= 1; off >>= 1) s += __shfl_xor(s, off, 64);
        if (tid == 0) atomicAdd(loss_sum, s);
    }
}

// MFCC: 64 rows/block, 4 threads/row. Thread q computes cos bins
// [q*10, q*10+10) (uniform cos-table reads -> SGPR), bins exchanged via
// padded LDS; then thread q scans codes [q*64, q*64+64) with uniform
// codebook reads. Pre-norm of x cancels (matmul is linear).
__global__ __launch_bounds__(256) void mfcc_vq_kernel(
    const float* __restrict__ X, const float* __restrict__ cb,
    const float* __restrict__ cn, const float* __restrict__ costab,
    float* __restrict__ out, int* __restrict__ counts,
    float* __restrict__ loss_sum)
{
    __shared__ float xm_lds[64][41];   // pad 41: bank stride 9 (coprime 32)
    __shared__ float red_d[256];
    __shared__ int   red_i[256];

    const int tid = threadIdx.x;
    const int rl  = tid & 63;
    const int qu  = __builtin_amdgcn_readfirstlane(tid >> 6);
    const size_t r = (size_t)blockIdx.x * 64 + rl;

    float x[DW];
    const float4* xp = (const float4*)(X + r * DW);
    #pragma unroll
    for (int i = 0; i < DW / 4; ++i) {
        float4 v = xp[i];
        x[4*i+0] = v.x; x[4*i+1] = v.y; x[4*i+2] = v.z; x[4*i+3] = v.w;
    }

    // transform: this thread's 10 bins
    const float* ct = costab + qu * 10;
    float xm[10];
    #pragma unroll
    for (int j = 0; j < 10; ++j) xm[j] = 0.f;
    for (int d = 0; d < DW; ++d) {
        float xd = x[d];
        const float* cr = ct + d * DMP;
        #pragma unroll
        for (int j = 0; j < 10; ++j) xm[j] = fmaf(xd, cr[j], xm[j]);
    }
    #pragma unroll
    for (int j = 0; j < 10; ++j) xm_lds[rl][qu * 10 + j] = xm[j];
    __syncthreads();

    float xf[DMP];
    #pragma unroll
    for (int j = 0; j < DMP; ++j) xf[j] = xm_lds[rl][j];
    float n2 = 0.f;
    #pragma unroll
    for (int j = 0; j < DM; ++j) n2 = fmaf(xf[j], xf[j], n2);
    float inv = 1.0f / fmaxf(sqrtf(n2), 1e-12f);
    #pragma unroll
    for (int j = 0; j < DM; ++j) xf[j] *= inv;

    const int cbase = qu * (KM / 4);
    float best = 3.4e38f; int bidx = cbase;
    for (int c = 0; c < KM / 4; ++c) {
        const float* cr = cb + (size_t)(cbase + c) * DM;
        float a0 = 0.f, a1 = 0.f, a2 = 0.f, a3 = 0.f;
        #pragma unroll
        for (int j = 0; j < 9; ++j) {
            a0 = fmaf(xf[4*j+0], cr[4*j+0], a0);
            a1 = fmaf(xf[4*j+1], cr[4*j+1], a1);
            a2 = fmaf(xf[4*j+2], cr[4*j+2], a2);
            a3 = fmaf(xf[4*j+3], cr[4*j+3], a3);
        }
        a0 = fmaf(xf[36], cr[36], a0);
        a1 = fmaf(xf[37], cr[37], a1);
        float d = cn[cbase + c] - 2.0f * ((a0 + a1) + (a2 + a3));
        if (d < best) { best = d; bidx = cbase + c; }
    }

    red_d[tid] = best; red_i[tid] = bidx;
    __syncthreads();
    if (tid < 64) {
        #pragma unroll
        for (int qq = 1; qq < 4; ++qq) {
            float d2 = red_d[qq * 64 + tid];
            int   i2 = red_i[qq * 64 + tid];
            if (d2 < best || (d2 == best && i2 < bidx)) { best = d2; bidx = i2; }
        }
        out[2 * r + 1] = (float)(bidx + KW);
        atomicAdd(&counts[bidx], 1);
        const float* qp = cb + (size_t)bidx * DM;
        float s = 0.f;
        #pragma unroll
        for (int j = 0; j < DM; ++j) {
            float df = xf[j] - qp[j];
            s = fmaf(df, df, s);
        }
        #pragma unroll
        for (int off = 32; off >= 1; off >>= 1) s += __shfl_xor(s, off, 64);
        if (tid == 0) atomicAdd(loss_sum, s);
    }
}

__global__ __launch_bounds__(256) void finalize_kernel(
    const int* __restrict__ counts_w, const int* __restrict__ counts_m,
    const float* __restrict__ sums, float* __restrict__ out)
{
    __shared__ float red[4];
    const int tid = threadIdx.x;
    const bool wv = (blockIdx.x == 0);
    const int K = wv ? KW : KM;
    const int* c = wv ? counts_w : counts_m;
    float s = 0.f;
    for (int i = tid; i < K; i += 256) {
        float p = (float)c[i] * (1.0f / 65536.0f);
        s += p * logf(p + 1e-10f);
    }
    #pragma unroll
    for (int off = 32; off >= 1; off >>= 1) s += __shfl_xor(s, off, 64);
    if ((tid & 63) == 0) red[tid >> 6] = s;
    __syncthreads();
    if (tid == 0) {
        float t = red[0] + red[1] + red[2] + red[3];
        float ppl = expf(-t);
        float denom = wv ? (float)(NROWS * DW) : (float)(NROWS * DM);
        int base = 2 * NROWS + (wv ? 0 : 2);
        out[base]     = ppl;
        out[base + 1] = 1.25f * sums[wv ? 0 : 1] / denom;
    }
}

extern "C" void kernel_launch(void* const* d_in, const int* in_sizes, int n_in,
                              void* d_out, int out_size, void* d_ws, size_t ws_size,
                              hipStream_t stream) {
    const float* X   = (const float*)d_in[0];
    const float* cbw = (const float*)d_in[1];
    const float* cbm = (const float*)d_in[2];
    float* out = (float*)d_out;

    char* ws = (char*)d_ws;
    int*   counts_w = (int*)(ws + 0);
    int*   counts_m = (int*)(ws + 4096);
    float* sums     = (float*)(ws + 5120);
    float* cn_w     = (float*)(ws + 5632);
    float* cn_m     = (float*)(ws + 9728);
    float* costab   = (float*)(ws + 10752);

    prep_kernel<<<18, 256, 0, stream>>>(cbw, cbm, counts_w, counts_m, sums,
                                        cn_w, cn_m, costab);
    wave_vq_kernel<<<NROWS / 64, 256, 0, stream>>>(X, cbw, cn_w, out,
                                                   counts_w, sums + 0);
    mfcc_vq_kernel<<<NROWS / 64, 256, 0, stream>>>(X, cbm, cn_m, costab, out,
                                                   counts_m, sums + 1);
    finalize_kernel<<<2, 256, 0, stream>>>(counts_w, counts_m, sums, out);
}

// Round 3
// 410.202 us; speedup vs baseline: 1.3755x; 1.3755x over previous
//
#include <hip/hip_runtime.h>
#include <hip/hip_bf16.h>
#include <math.h>

// ---------------------------------------------------------------------------
// AudioVQMix. Wave VQ = bf16-split-product MFMA GEMM (4 products ~ fp32-exact)
// over 1024 codes, D=80 (padded to 96). mfcc = streaming cos-matmul (80->38,
// pre-norm cancels) + l2norm + VALU VQ over 256 codes. Losses: wave loss
// folded into mfcc kernel (it streams x anyway and reads wave idx from out).
// Output (f32): [0..131071] encodings, then wave_ppl, wave_loss, mfcc_ppl,
// mfcc_loss.
// ---------------------------------------------------------------------------

#define NROWS 65536
#define DW    80
#define KW    1024
#define DM    38
#define DMP   40
#define KM    256
#define CHUNK 128              // wave codes per staged chunk
#define NCHK  (KW / CHUNK)     // 8
#define CT_PER (CHUNK / 16)    // 8 col-tiles of 16

typedef __attribute__((ext_vector_type(8))) short bf16x8;
typedef __attribute__((ext_vector_type(4))) float f32x4;

__device__ __forceinline__ void bf16split(float v, short& h, short& l) {
    __hip_bfloat16 hb = __float2bfloat16(v);
    float hf = __bfloat162float(hb);
    __hip_bfloat16 lb = __float2bfloat16(v - hf);
    h = *(short*)&hb;
    l = *(short*)&lb;
}

// workspace layout (bytes)
//   0     : counts_w (1024 i32)
//   4096  : counts_m (256 i32)
//   5120  : sums (2 f32: wave_loss_sum, mfcc_loss_sum)
//   5632  : cn_w (1024 f32)
//   9728  : cn_m (256 f32)
//   10752 : costab (80*40 f32)

__global__ __launch_bounds__(256) void prep_kernel(
    const float* __restrict__ cbw, const float* __restrict__ cbm,
    int* __restrict__ counts_w, int* __restrict__ counts_m,
    float* __restrict__ sums, float* __restrict__ cn_w,
    float* __restrict__ cn_m, float* __restrict__ costab)
{
    int idx = blockIdx.x * 256 + threadIdx.x;
    if (idx < KW) {
        counts_w[idx] = 0;
        const float* p = cbw + (size_t)idx * DW;
        float s = 0.f;
        for (int i = 0; i < DW; ++i) s = fmaf(p[i], p[i], s);
        cn_w[idx] = s;
    } else if (idx < KW + KM) {
        int i = idx - KW;
        counts_m[i] = 0;
        const float* p = cbm + (size_t)i * DM;
        float s = 0.f;
        for (int j = 0; j < DM; ++j) s = fmaf(p[j], p[j], s);
        cn_m[i] = s;
    } else if (idx < KW + KM + DW * DMP) {
        int t = idx - (KW + KM);
        int d = t / DMP, j = t % DMP;
        double v = (j < DM)
            ? cos(2.0 * 3.14159265358979323846 * (double)((j + 2) * d) / 80.0)
            : 0.0;
        costab[t] = (float)v;
    } else if (idx == KW + KM + DW * DMP)     sums[0] = 0.f;
    else if (idx == KW + KM + DW * DMP + 1)   sums[1] = 0.f;
}

// ---------------------------------------------------------------------------
// Wave VQ via MFMA. Block = 256 rows (4 waves x 64 rows = 4 row-tiles of 16).
// All waves share a 128-code chunk staged in LDS as bf16 hi/lo fragments
// (double-buffered). Per (ct,s): 2 ds_read_b128, 16 MFMA.
// A-frag: lane l holds rows c16=l&15, k = 32s + 8*(l>>4) + j (zeros for k>=80).
// C/D: col = lane&15, row = 4*(lane>>4) + reg  [HW-verified m89/m91].
// ---------------------------------------------------------------------------
__global__ __launch_bounds__(256) void wave_vq_mfma(
    const float* __restrict__ X, const float* __restrict__ cb,
    const float* __restrict__ cn, float* __restrict__ out,
    int* __restrict__ counts)
{
    __shared__ short Bh[2][CT_PER * 3 * 64 * 8];   // 2 x 24 KB
    __shared__ short Bl[2][CT_PER * 3 * 64 * 8];   // 2 x 24 KB
    __shared__ float cnl[2][CHUNK];

    const int tid = threadIdx.x;
    const int l   = tid & 63;
    const int qu  = tid >> 6;
    const int c16 = l & 15;
    const int g   = l >> 4;
    const size_t rowbase = (size_t)blockIdx.x * 256 + (size_t)qu * 64;

    // ---- load + split-convert A fragments (x rows) into registers ----
    bf16x8 Ah[4][3], Al[4][3];
    #pragma unroll
    for (int rt = 0; rt < 4; ++rt) {
        #pragma unroll
        for (int s = 0; s < 3; ++s) {
            const int k0 = 32 * s + 8 * g;
            bf16x8 ah, al;
            if (k0 < DW) {
                const float4* ap =
                    (const float4*)(X + (rowbase + rt * 16 + c16) * DW + k0);
                float4 u = ap[0], w = ap[1];
                float f[8] = {u.x, u.y, u.z, u.w, w.x, w.y, w.z, w.w};
                #pragma unroll
                for (int j = 0; j < 8; ++j) {
                    short hh, ll;
                    bf16split(f[j], hh, ll);
                    ah[j] = hh; al[j] = ll;
                }
            } else {
                #pragma unroll
                for (int j = 0; j < 8; ++j) { ah[j] = 0; al[j] = 0; }
            }
            Ah[rt][s] = ah; Al[rt][s] = al;
        }
    }

    // ---- zero the k=80..96 pad region of both B buffers (once) ----
    for (int i = tid; i < CT_PER * 32 * 8; i += 256) {
        int ctt = i >> 8;
        int rem = i & 255;
        int lane = 32 + (rem >> 3), j = rem & 7;
        int off = ((ctt * 3 + 2) * 64 + lane) * 8 + j;
        Bh[0][off] = 0; Bh[1][off] = 0; Bl[0][off] = 0; Bl[1][off] = 0;
    }

    // ---- staging: 128 codes -> fragment-ordered bf16 hi/lo in LDS ----
    auto stage = [&](int c, int b) {
        const float4* src = (const float4*)(cb + (size_t)c * CHUNK * DW);
        #pragma unroll
        for (int i = 0; i < 10; ++i) {
            int q4 = i * 256 + tid;          // float4 index in chunk
            float4 v = src[q4];
            int cl = q4 / 20;                // local code 0..127
            int kb = (q4 - cl * 20) * 4;     // k base (mult of 4)
            int ctt = cl >> 4, cc = cl & 15;
            int s = kb >> 5, kl = kb & 31, gg = kl >> 3, j0 = kl & 7;
            int off = ((ctt * 3 + s) * 64 + gg * 16 + cc) * 8 + j0;
            short h0, h1, h2, h3, l0, l1, l2, l3;
            bf16split(v.x, h0, l0); bf16split(v.y, h1, l1);
            bf16split(v.z, h2, l2); bf16split(v.w, h3, l3);
            short4 hv = {h0, h1, h2, h3}, lv = {l0, l1, l2, l3};
            *(short4*)&Bh[b][off] = hv;
            *(short4*)&Bl[b][off] = lv;
        }
        if (tid < CHUNK) cnl[b][tid] = cn[c * CHUNK + tid];
    };

    stage(0, 0);
    __syncthreads();

    float bd[4][4];
    int   bi[4][4];
    #pragma unroll
    for (int rt = 0; rt < 4; ++rt)
        #pragma unroll
        for (int i = 0; i < 4; ++i) { bd[rt][i] = 3.4e38f; bi[rt][i] = 0; }

    for (int ch = 0; ch < NCHK; ++ch) {
        const int cur = ch & 1;

        for (int ct = 0; ct < CT_PER; ++ct) {
            const float cnv = cnl[cur][ct * 16 + c16];
            f32x4 acc[4];
            #pragma unroll
            for (int rt = 0; rt < 4; ++rt) acc[rt] = (f32x4){0.f, 0.f, 0.f, 0.f};

            #pragma unroll
            for (int s = 0; s < 3; ++s) {
                const int bo = ((ct * 3 + s) * 64 + l) * 8;
                bf16x8 bh = *(const bf16x8*)&Bh[cur][bo];
                bf16x8 bl = *(const bf16x8*)&Bl[cur][bo];
                #pragma unroll
                for (int rt = 0; rt < 4; ++rt)
                    acc[rt] = __builtin_amdgcn_mfma_f32_16x16x32_bf16(Al[rt][s], bl, acc[rt], 0, 0, 0);
                #pragma unroll
                for (int rt = 0; rt < 4; ++rt)
                    acc[rt] = __builtin_amdgcn_mfma_f32_16x16x32_bf16(Ah[rt][s], bl, acc[rt], 0, 0, 0);
                #pragma unroll
                for (int rt = 0; rt < 4; ++rt)
                    acc[rt] = __builtin_amdgcn_mfma_f32_16x16x32_bf16(Al[rt][s], bh, acc[rt], 0, 0, 0);
                #pragma unroll
                for (int rt = 0; rt < 4; ++rt)
                    acc[rt] = __builtin_amdgcn_mfma_f32_16x16x32_bf16(Ah[rt][s], bh, acc[rt], 0, 0, 0);
            }

            const int idxbase = ch * CHUNK + ct * 16 + c16;
            #pragma unroll
            for (int rt = 0; rt < 4; ++rt) {
                #pragma unroll
                for (int i = 0; i < 4; ++i) {
                    float d = fmaf(-2.f, acc[rt][i], cnv);
                    if (d < bd[rt][i]) { bd[rt][i] = d; bi[rt][i] = idxbase; }
                }
            }
        }

        if (ch + 1 < NCHK) stage(ch + 1, cur ^ 1);
        __syncthreads();
    }

    // ---- reduce across the 16 lanes holding each row's columns ----
    #pragma unroll
    for (int rt = 0; rt < 4; ++rt) {
        #pragma unroll
        for (int i = 0; i < 4; ++i) {
            float d = bd[rt][i]; int ix = bi[rt][i];
            #pragma unroll
            for (int m = 1; m < 16; m <<= 1) {
                float d2 = __shfl_xor(d, m, 64);
                int   i2 = __shfl_xor(ix, m, 64);
                if (d2 < d || (d2 == d && i2 < ix)) { d = d2; ix = i2; }
            }
            if (c16 == 0) {
                size_t row = rowbase + rt * 16 + 4 * g + i;
                out[2 * row] = (float)ix;
                atomicAdd(&counts[ix], 1);
            }
        }
    }
}

// ---------------------------------------------------------------------------
// MFCC: 64 rows/block, 4 thr/row. Streaming transform (no x[] array -> no
// scratch). Thread qu computes bins [qu*10, qu*10+10); wave 0's threads also
// accumulate the wave-VQ loss (reads wave idx from out[2r]). Bins exchanged
// via padded LDS, l2norm, VQ over code range [qu*64, qu*64+64).
// ---------------------------------------------------------------------------
__global__ __launch_bounds__(256) void mfcc_vq_kernel(
    const float* __restrict__ X, const float* __restrict__ cbw,
    const float* __restrict__ cb, const float* __restrict__ cn,
    const float* __restrict__ costab, float* __restrict__ out,
    int* __restrict__ counts, float* __restrict__ sums)
{
    __shared__ float xm_lds[64][41];
    __shared__ float red_d[256];
    __shared__ int   red_i[256];

    const int tid = threadIdx.x;
    const int rl  = tid & 63;
    const int qu  = __builtin_amdgcn_readfirstlane(tid >> 6);
    const size_t r = (size_t)blockIdx.x * 64 + rl;

    const float4* xr = (const float4*)(X + r * DW);
    const int widx = (int)out[2 * r];
    const float4* cwr = (const float4*)(cbw + (size_t)widx * DW);
    const float* ctb = costab + qu * 10;

    float xm[10];
    #pragma unroll
    for (int j = 0; j < 10; ++j) xm[j] = 0.f;
    float lw = 0.f;

    #pragma unroll
    for (int d4 = 0; d4 < 20; ++d4) {
        float4 x4 = xr[d4];
        if (qu == 0) {
            float4 c4 = cwr[d4];
            float e0 = x4.x - c4.x, e1 = x4.y - c4.y;
            float e2 = x4.z - c4.z, e3 = x4.w - c4.w;
            lw = fmaf(e0, e0, lw); lw = fmaf(e1, e1, lw);
            lw = fmaf(e2, e2, lw); lw = fmaf(e3, e3, lw);
        }
        float xs[4] = {x4.x, x4.y, x4.z, x4.w};
        #pragma unroll
        for (int e = 0; e < 4; ++e) {
            const float* cr = ctb + (size_t)(4 * d4 + e) * DMP;
            #pragma unroll
            for (int j = 0; j < 10; ++j) xm[j] = fmaf(xs[e], cr[j], xm[j]);
        }
    }

    if (qu == 0) {
        #pragma unroll
        for (int off = 32; off >= 1; off >>= 1) lw += __shfl_xor(lw, off, 64);
        if (tid == 0) atomicAdd(&sums[0], lw);
    }

    #pragma unroll
    for (int j = 0; j < 10; ++j) xm_lds[rl][qu * 10 + j] = xm[j];
    __syncthreads();

    float xf[DMP];
    #pragma unroll
    for (int j = 0; j < DMP; ++j) xf[j] = xm_lds[rl][j];
    float n2 = 0.f;
    #pragma unroll
    for (int j = 0; j < DM; ++j) n2 = fmaf(xf[j], xf[j], n2);
    float inv = 1.0f / fmaxf(sqrtf(n2), 1e-12f);
    #pragma unroll
    for (int j = 0; j < DM; ++j) xf[j] *= inv;

    const int cbase = qu * (KM / 4);
    float best = 3.4e38f; int bidx = cbase;
    for (int c = 0; c < KM / 4; ++c) {
        const float* cr = cb + (size_t)(cbase + c) * DM;
        float a0 = 0.f, a1 = 0.f, a2 = 0.f, a3 = 0.f;
        #pragma unroll
        for (int j = 0; j < 9; ++j) {
            a0 = fmaf(xf[4*j+0], cr[4*j+0], a0);
            a1 = fmaf(xf[4*j+1], cr[4*j+1], a1);
            a2 = fmaf(xf[4*j+2], cr[4*j+2], a2);
            a3 = fmaf(xf[4*j+3], cr[4*j+3], a3);
        }
        a0 = fmaf(xf[36], cr[36], a0);
        a1 = fmaf(xf[37], cr[37], a1);
        float d = cn[cbase + c] - 2.0f * ((a0 + a1) + (a2 + a3));
        if (d < best) { best = d; bidx = cbase + c; }
    }

    red_d[tid] = best; red_i[tid] = bidx;
    __syncthreads();
    if (tid < 64) {
        #pragma unroll
        for (int qq = 1; qq < 4; ++qq) {
            float d2 = red_d[qq * 64 + tid];
            int   i2 = red_i[qq * 64 + tid];
            if (d2 < best || (d2 == best && i2 < bidx)) { best = d2; bidx = i2; }
        }
        out[2 * r + 1] = (float)(bidx + KW);
        atomicAdd(&counts[bidx], 1);
        const float* qp = cb + (size_t)bidx * DM;
        float s = 0.f;
        #pragma unroll
        for (int j = 0; j < DM; ++j) {
            float df = xf[j] - qp[j];
            s = fmaf(df, df, s);
        }
        #pragma unroll
        for (int off = 32; off >= 1; off >>= 1) s += __shfl_xor(s, off, 64);
        if (tid == 0) atomicAdd(&sums[1], s);
    }
}

__global__ __launch_bounds__(256) void finalize_kernel(
    const int* __restrict__ counts_w, const int* __restrict__ counts_m,
    const float* __restrict__ sums, float* __restrict__ out)
{
    __shared__ float red[4];
    const int tid = threadIdx.x;
    const bool wv = (blockIdx.x == 0);
    const int K = wv ? KW : KM;
    const int* c = wv ? counts_w : counts_m;
    float s = 0.f;
    for (int i = tid; i < K; i += 256) {
        float p = (float)c[i] * (1.0f / 65536.0f);
        s += p * logf(p + 1e-10f);
    }
    #pragma unroll
    for (int off = 32; off >= 1; off >>= 1) s += __shfl_xor(s, off, 64);
    if ((tid & 63) == 0) red[tid >> 6] = s;
    __syncthreads();
    if (tid == 0) {
        float t = red[0] + red[1] + red[2] + red[3];
        float ppl = expf(-t);
        float denom = wv ? (float)(NROWS * DW) : (float)(NROWS * DM);
        int base = 2 * NROWS + (wv ? 0 : 2);
        out[base]     = ppl;
        out[base + 1] = 1.25f * sums[wv ? 0 : 1] / denom;
    }
}

extern "C" void kernel_launch(void* const* d_in, const int* in_sizes, int n_in,
                              void* d_out, int out_size, void* d_ws, size_t ws_size,
                              hipStream_t stream) {
    const float* X   = (const float*)d_in[0];
    const float* cbw = (const float*)d_in[1];
    const float* cbm = (const float*)d_in[2];
    float* out = (float*)d_out;

    char* ws = (char*)d_ws;
    int*   counts_w = (int*)(ws + 0);
    int*   counts_m = (int*)(ws + 4096);
    float* sums     = (float*)(ws + 5120);
    float* cn_w     = (float*)(ws + 5632);
    float* cn_m     = (float*)(ws + 9728);
    float* costab   = (float*)(ws + 10752);

    prep_kernel<<<18, 256, 0, stream>>>(cbw, cbm, counts_w, counts_m, sums,
                                        cn_w, cn_m, costab);
    wave_vq_mfma<<<NROWS / 256, 256, 0, stream>>>(X, cbw, cn_w, out, counts_w);
    mfcc_vq_kernel<<<NROWS / 64, 256, 0, stream>>>(X, cbw, cbm, cn_m, costab,
                                                   out, counts_m, sums);
    finalize_kernel<<<2, 256, 0, stream>>>(counts_w, counts_m, sums, out);
}

// Round 5
// 107.015 us; speedup vs baseline: 5.2727x; 3.8331x over previous
//
#include <hip/hip_runtime.h>
#include <hip/hip_bf16.h>
#include <math.h>

// ---------------------------------------------------------------------------
// AudioVQMix. Wave VQ = 2-term bf16-split MFMA GEMM (verified exact r3).
// mfcc = 3-term bf16-split MFMA transform (80->48 cos table, pre-norm
// cancels) + f32 l2norm + 3-term-split MFMA VQ (error ~1e-6 vs f32 ref).
// Losses derived from GEMM distances; histogram via LDS+global atomics.
// Output (f32): [0..131071] encodings, then wave_ppl, wave_loss, mfcc_ppl,
// mfcc_loss.
// ---------------------------------------------------------------------------

#define NROWS 65536
#define DW    80
#define KW    1024
#define DM    38
#define KM    256
#define CHUNK 128
#define NCHK  8
#define CT_PER 8

typedef __attribute__((ext_vector_type(8))) short bf16x8;
typedef __attribute__((ext_vector_type(4))) float f32x4;

__device__ __forceinline__ void bf16split(float v, short& h, short& l) {
    __hip_bfloat16 hb = __float2bfloat16(v);
    float hf = __bfloat162float(hb);
    __hip_bfloat16 lb = __float2bfloat16(v - hf);
    h = *(short*)&hb;
    l = *(short*)&lb;
}

__device__ __forceinline__ void bf16split3(float v, short& a, short& b, short& c) {
    __hip_bfloat16 h = __float2bfloat16(v);
    float hf = __bfloat162float(h);
    float r = v - hf;
    __hip_bfloat16 m = __float2bfloat16(r);
    float mf = __bfloat162float(m);
    __hip_bfloat16 lo = __float2bfloat16(r - mf);
    a = *(short*)&h; b = *(short*)&m; c = *(short*)&lo;
}

__device__ __forceinline__ bf16x8 bf8zero() {
    bf16x8 z;
    #pragma unroll
    for (int j = 0; j < 8; ++j) z[j] = 0;
    return z;
}

// workspace layout (bytes)
#define WS_SUMS   0        // 2 f32
#define WS_HIST   256      // 1280 i32 = 5120 B
#define WS_CNW    5376     // 1024 f32
#define WS_CNM    9472     // 256 f32
#define WS_COSTAB 10496    // 80*40 f32 = 12800 B
#define WS_CTF    23296    // 3 comps x 3840 shorts = 23040 B
#define WS_CBF    46336    // 3 comps x 12288 shorts = 73728 B (end 120064)

__global__ __launch_bounds__(256) void prep_kernel(
    const float* __restrict__ cbw, const float* __restrict__ cbm,
    float* __restrict__ sums, int* __restrict__ hist,
    float* __restrict__ cn_w, float* __restrict__ cn_m,
    float* __restrict__ costab)
{
    int idx = blockIdx.x * 256 + threadIdx.x;
    if (idx < KW) {
        const float* p = cbw + (size_t)idx * DW;
        float s = 0.f;
        for (int i = 0; i < DW; ++i) s = fmaf(p[i], p[i], s);
        cn_w[idx] = s;
    } else if (idx < KW + KM) {
        int i = idx - KW;
        const float* p = cbm + (size_t)i * DM;
        float s = 0.f;
        for (int j = 0; j < DM; ++j) s = fmaf(p[j], p[j], s);
        cn_m[i] = s;
    } else if (idx < KW + KM + DW * 40) {
        int t = idx - (KW + KM);
        int d = t / 40, j = t % 40;
        double v = (j < DM)
            ? cos(2.0 * 3.14159265358979323846 * (double)((j + 2) * d) / 80.0)
            : 0.0;
        costab[t] = (float)v;
    } else if (idx == KW + KM + DW * 40)      sums[0] = 0.f;
    else if (idx == KW + KM + DW * 40 + 1)    sums[1] = 0.f;
    else if (idx >= 4482 && idx < 4482 + 1280) hist[idx - 4482] = 0;
}

// 3-term fragment tables for mfcc transform B (cos) and mfcc codebook B.
// CT layout per comp (3840 shorts): s<2: ((ct*2+s)*64+l)*8+j  (k=32s+8g+j)
//                                   s=2: 3072+(ct*32+l)*8+j, l<32 (k=64+8g+j)
// CB layout per comp (12288 shorts): k<32: (ct*64+l)*8+j
//                                    k>=32: 8192+(ct*32+l)*8+j, l<32
__global__ __launch_bounds__(256) void prep2_kernel(
    const float* __restrict__ costab, const float* __restrict__ cbm,
    short* __restrict__ ctf, short* __restrict__ cbf)
{
    int idx = blockIdx.x * 256 + threadIdx.x;
    if (idx < 3840) {
        int col, k;
        if (idx < 3072) {
            int j = idx & 7, l = (idx >> 3) & 63, t = idx >> 9;
            col = (t >> 1) * 16 + (l & 15);
            k = 32 * (t & 1) + 8 * (l >> 4) + j;
        } else {
            int i2 = idx - 3072;
            int j = i2 & 7, l = (i2 >> 3) & 31, ct = i2 >> 8;
            col = ct * 16 + (l & 15);
            k = 64 + 8 * (l >> 4) + j;
        }
        float v = (col < 40) ? costab[k * 40 + col] : 0.f;
        short a, b, c; bf16split3(v, a, b, c);
        ctf[idx] = a; ctf[3840 + idx] = b; ctf[7680 + idx] = c;
    } else if (idx < 16128) {
        int i3 = idx - 3840;
        int code, k;
        if (i3 < 8192) {
            int j = i3 & 7, l = (i3 >> 3) & 63, ct = i3 >> 9;
            code = ct * 16 + (l & 15);
            k = 8 * (l >> 4) + j;
        } else {
            int i4 = i3 - 8192;
            int j = i4 & 7, l = (i4 >> 3) & 31, ct = i4 >> 8;
            code = ct * 16 + (l & 15);
            k = 32 + 8 * (l >> 4) + j;
        }
        float v = (k < DM) ? cbm[(size_t)code * DM + k] : 0.f;
        short a, b, c; bf16split3(v, a, b, c);
        cbf[i3] = a; cbf[12288 + i3] = b; cbf[24576 + i3] = c;
    }
}

// ---------------------------------------------------------------------------
// Wave VQ via MFMA — index path bit-identical to round-3-verified kernel.
// ---------------------------------------------------------------------------
__global__ __launch_bounds__(256) void wave_vq_mfma(
    const float* __restrict__ X, const float* __restrict__ cb,
    const float* __restrict__ cn, float* __restrict__ out,
    float* __restrict__ sums)
{
    __shared__ short Bh[2][CT_PER * 3 * 64 * 8];
    __shared__ short Bl[2][CT_PER * 3 * 64 * 8];
    __shared__ float cnl[2][CHUNK];
    __shared__ float redw[4];

    const int tid = threadIdx.x;
    const int l   = tid & 63;
    const int qu  = tid >> 6;
    const int c16 = l & 15;
    const int g   = l >> 4;
    const size_t rowbase = (size_t)blockIdx.x * 256 + (size_t)qu * 64;

    bf16x8 Ah[4][3], Al[4][3];
    float xs2[4] = {0.f, 0.f, 0.f, 0.f};
    #pragma unroll
    for (int rt = 0; rt < 4; ++rt) {
        #pragma unroll
        for (int s = 0; s < 3; ++s) {
            const int k0 = 32 * s + 8 * g;
            bf16x8 ah, al;
            if (k0 < DW) {
                const float4* ap =
                    (const float4*)(X + (rowbase + rt * 16 + c16) * DW + k0);
                float4 u = ap[0], w = ap[1];
                float f[8] = {u.x, u.y, u.z, u.w, w.x, w.y, w.z, w.w};
                #pragma unroll
                for (int j = 0; j < 8; ++j) {
                    short hh, ll;
                    bf16split(f[j], hh, ll);
                    ah[j] = hh; al[j] = ll;
                    xs2[rt] = fmaf(f[j], f[j], xs2[rt]);
                }
            } else {
                ah = bf8zero(); al = bf8zero();
            }
            Ah[rt][s] = ah; Al[rt][s] = al;
        }
    }
    #pragma unroll
    for (int rt = 0; rt < 4; ++rt) {
        xs2[rt] += __shfl_xor(xs2[rt], 16, 64);
        xs2[rt] += __shfl_xor(xs2[rt], 32, 64);
    }

    for (int i = tid; i < CT_PER * 32 * 8; i += 256) {
        int ctt = i >> 8;
        int rem = i & 255;
        int lane = 32 + (rem >> 3), j = rem & 7;
        int off = ((ctt * 3 + 2) * 64 + lane) * 8 + j;
        Bh[0][off] = 0; Bh[1][off] = 0; Bl[0][off] = 0; Bl[1][off] = 0;
    }

    auto stage = [&](int c, int b) {
        const float4* src = (const float4*)(cb + (size_t)c * CHUNK * DW);
        #pragma unroll
        for (int i = 0; i < 10; ++i) {
            int q4 = i * 256 + tid;
            float4 v = src[q4];
            int cl = q4 / 20;
            int kb = (q4 - cl * 20) * 4;
            int ctt = cl >> 4, cc = cl & 15;
            int s = kb >> 5, kl = kb & 31, gg = kl >> 3, j0 = kl & 7;
            int off = ((ctt * 3 + s) * 64 + gg * 16 + cc) * 8 + j0;
            short h0, h1, h2, h3, l0, l1, l2, l3;
            bf16split(v.x, h0, l0); bf16split(v.y, h1, l1);
            bf16split(v.z, h2, l2); bf16split(v.w, h3, l3);
            short4 hv = {h0, h1, h2, h3}, lv = {l0, l1, l2, l3};
            *(short4*)&Bh[b][off] = hv;
            *(short4*)&Bl[b][off] = lv;
        }
        if (tid < CHUNK) cnl[b][tid] = cn[c * CHUNK + tid];
    };

    stage(0, 0);
    __syncthreads();

    float bd[4][4];
    int   bi[4][4];
    #pragma unroll
    for (int rt = 0; rt < 4; ++rt)
        #pragma unroll
        for (int i = 0; i < 4; ++i) { bd[rt][i] = 3.4e38f; bi[rt][i] = 0; }

    for (int ch = 0; ch < NCHK; ++ch) {
        const int cur = ch & 1;
        for (int ct = 0; ct < CT_PER; ++ct) {
            const float cnv = cnl[cur][ct * 16 + c16];
            f32x4 acc[4];
            #pragma unroll
            for (int rt = 0; rt < 4; ++rt) acc[rt] = (f32x4){0.f, 0.f, 0.f, 0.f};
            #pragma unroll
            for (int s = 0; s < 3; ++s) {
                const int bo = ((ct * 3 + s) * 64 + l) * 8;
                bf16x8 bh = *(const bf16x8*)&Bh[cur][bo];
                bf16x8 bl = *(const bf16x8*)&Bl[cur][bo];
                #pragma unroll
                for (int rt = 0; rt < 4; ++rt)
                    acc[rt] = __builtin_amdgcn_mfma_f32_16x16x32_bf16(Al[rt][s], bl, acc[rt], 0, 0, 0);
                #pragma unroll
                for (int rt = 0; rt < 4; ++rt)
                    acc[rt] = __builtin_amdgcn_mfma_f32_16x16x32_bf16(Ah[rt][s], bl, acc[rt], 0, 0, 0);
                #pragma unroll
                for (int rt = 0; rt < 4; ++rt)
                    acc[rt] = __builtin_amdgcn_mfma_f32_16x16x32_bf16(Al[rt][s], bh, acc[rt], 0, 0, 0);
                #pragma unroll
                for (int rt = 0; rt < 4; ++rt)
                    acc[rt] = __builtin_amdgcn_mfma_f32_16x16x32_bf16(Ah[rt][s], bh, acc[rt], 0, 0, 0);
            }
            const int idxbase = ch * CHUNK + ct * 16 + c16;
            #pragma unroll
            for (int rt = 0; rt < 4; ++rt) {
                #pragma unroll
                for (int i = 0; i < 4; ++i) {
                    float d = fmaf(-2.f, acc[rt][i], cnv);
                    if (d < bd[rt][i]) { bd[rt][i] = d; bi[rt][i] = idxbase; }
                }
            }
        }
        if (ch + 1 < NCHK) stage(ch + 1, cur ^ 1);
        __syncthreads();
    }

    float lw = 0.f;
    #pragma unroll
    for (int rt = 0; rt < 4; ++rt) {
        #pragma unroll
        for (int i = 0; i < 4; ++i) {
            float d = bd[rt][i]; int ix = bi[rt][i];
            #pragma unroll
            for (int m = 1; m < 16; m <<= 1) {
                float d2 = __shfl_xor(d, m, 64);
                int   i2 = __shfl_xor(ix, m, 64);
                if (d2 < d || (d2 == d && i2 < ix)) { d = d2; ix = i2; }
            }
            float xn = __shfl(xs2[rt], (l & 48) + 4 * (l >> 4) + i, 64);
            if (c16 == 0) {
                size_t row = rowbase + rt * 16 + 4 * g + i;
                out[2 * row] = (float)ix;
                lw += d + xn;
            }
        }
    }
    #pragma unroll
    for (int m = 1; m < 64; m <<= 1) lw += __shfl_xor(lw, m, 64);
    if (l == 0) redw[qu] = lw;
    __syncthreads();
    if (tid == 0) atomicAdd(&sums[0], redw[0] + redw[1] + redw[2] + redw[3]);
}

// ---------------------------------------------------------------------------
// MFCC via MFMA, 3-term splits throughout (error ~1e-6 vs f32 reference).
// Transform GEMM (N=48, K=96) per rt-tile -> f32 l2norm in C-layout -> f32
// xf in LDS -> re-split 3-term at read -> VQ GEMM (N=256, K=48).
// ---------------------------------------------------------------------------
__global__ __launch_bounds__(256) void mfcc_mfma(
    const float* __restrict__ X, const float* __restrict__ cn_m,
    const short* __restrict__ ctf, const short* __restrict__ cbf,
    float* __restrict__ out, float* __restrict__ sums)
{
    __shared__ __align__(16) short CT2[11520];   // 23040 B
    __shared__ __align__(16) short CB2[36864];   // 73728 B
    __shared__ float XF[4][64 * 49];             // 50176 B
    __shared__ float CN[KM];
    __shared__ float red4[4];

    const int tid = threadIdx.x;
    const int l   = tid & 63;
    const int w   = tid >> 6;
    const int c16 = l & 15;
    const int g   = l >> 4;
    const size_t rowbase = (size_t)blockIdx.x * 256 + (size_t)w * 64;

    {
        const int4* s1 = (const int4*)ctf;
        for (int i = tid; i < 1440; i += 256) ((int4*)CT2)[i] = s1[i];
        const int4* s2 = (const int4*)cbf;
        for (int i = tid; i < 4608; i += 256) ((int4*)CB2)[i] = s2[i];
        if (tid < KM) CN[tid] = cn_m[tid];
    }
    __syncthreads();

    float* xfl = &XF[w][0];

    // ---- transform, one rt-tile at a time ----
    #pragma unroll 1
    for (int rt = 0; rt < 4; ++rt) {
        bf16x8 A0[3], A1[3], A2[3];
        #pragma unroll
        for (int s = 0; s < 3; ++s) {
            const int k0 = 32 * s + 8 * g;
            if (k0 < DW) {
                const float4* ap =
                    (const float4*)(X + (rowbase + rt * 16 + c16) * DW + k0);
                float4 u = ap[0], v = ap[1];
                float f[8] = {u.x, u.y, u.z, u.w, v.x, v.y, v.z, v.w};
                bf16x8 a0, a1, a2;
                #pragma unroll
                for (int j = 0; j < 8; ++j) {
                    short aa, bb, cc;
                    bf16split3(f[j], aa, bb, cc);
                    a0[j] = aa; a1[j] = bb; a2[j] = cc;
                }
                A0[s] = a0; A1[s] = a1; A2[s] = a2;
            } else {
                A0[s] = bf8zero(); A1[s] = bf8zero(); A2[s] = bf8zero();
            }
        }

        f32x4 acc[3];
        #pragma unroll
        for (int ct = 0; ct < 3; ++ct) acc[ct] = (f32x4){0.f, 0.f, 0.f, 0.f};

        #pragma unroll
        for (int s = 0; s < 3; ++s) {
            #pragma unroll
            for (int ct = 0; ct < 3; ++ct) {
                bf16x8 b0, b1, b2;
                if (s < 2) {
                    const int off = ((ct * 2 + s) * 64 + l) * 8;
                    b0 = *(const bf16x8*)&CT2[off];
                    b1 = *(const bf16x8*)&CT2[3840 + off];
                    b2 = *(const bf16x8*)&CT2[7680 + off];
                } else if (l < 32) {
                    const int off = 3072 + (ct * 32 + l) * 8;
                    b0 = *(const bf16x8*)&CT2[off];
                    b1 = *(const bf16x8*)&CT2[3840 + off];
                    b2 = *(const bf16x8*)&CT2[7680 + off];
                } else {
                    b0 = bf8zero(); b1 = bf8zero(); b2 = bf8zero();
                }
                // small tiers first
                acc[ct] = __builtin_amdgcn_mfma_f32_16x16x32_bf16(A2[s], b0, acc[ct], 0, 0, 0);
                acc[ct] = __builtin_amdgcn_mfma_f32_16x16x32_bf16(A1[s], b1, acc[ct], 0, 0, 0);
                acc[ct] = __builtin_amdgcn_mfma_f32_16x16x32_bf16(A0[s], b2, acc[ct], 0, 0, 0);
                acc[ct] = __builtin_amdgcn_mfma_f32_16x16x32_bf16(A1[s], b0, acc[ct], 0, 0, 0);
                acc[ct] = __builtin_amdgcn_mfma_f32_16x16x32_bf16(A0[s], b1, acc[ct], 0, 0, 0);
                acc[ct] = __builtin_amdgcn_mfma_f32_16x16x32_bf16(A0[s], b0, acc[ct], 0, 0, 0);
            }
        }

        #pragma unroll
        for (int i = 0; i < 4; ++i) {
            float n2 = acc[0][i] * acc[0][i];
            n2 = fmaf(acc[1][i], acc[1][i], n2);
            n2 = fmaf(acc[2][i], acc[2][i], n2);
            #pragma unroll
            for (int m = 1; m < 16; m <<= 1) n2 += __shfl_xor(n2, m, 64);
            float inv = 1.0f / fmaxf(sqrtf(n2), 1e-12f);
            const int row_l = rt * 16 + 4 * g + i;
            #pragma unroll
            for (int ct = 0; ct < 3; ++ct)
                xfl[row_l * 49 + ct * 16 + c16] = acc[ct][i] * inv;
        }
    }
    __syncthreads();

    // ---- VQ A-frags: re-split xf (f32-exact) into 3 bf16 terms ----
    bf16x8 X0[4][3], X1[4][3];
    #pragma unroll
    for (int rt = 0; rt < 4; ++rt) {
        const int r0 = rt * 16 + c16;
        {
            const float* p = &xfl[r0 * 49 + 8 * g];
            bf16x8 q0, q1, q2;
            #pragma unroll
            for (int j = 0; j < 8; ++j) {
                short aa, bb, cc;
                bf16split3(p[j], aa, bb, cc);
                q0[j] = aa; q1[j] = bb; q2[j] = cc;
            }
            X0[rt][0] = q0; X0[rt][1] = q1; X0[rt][2] = q2;
        }
        if (g < 2) {
            const float* p = &xfl[r0 * 49 + 32 + 8 * g];
            bf16x8 q0, q1, q2;
            #pragma unroll
            for (int j = 0; j < 8; ++j) {
                short aa, bb, cc;
                bf16split3(p[j], aa, bb, cc);
                q0[j] = aa; q1[j] = bb; q2[j] = cc;
            }
            X1[rt][0] = q0; X1[rt][1] = q1; X1[rt][2] = q2;
        } else {
            X1[rt][0] = bf8zero(); X1[rt][1] = bf8zero(); X1[rt][2] = bf8zero();
        }
    }

    float bd[4][4];
    int   bi[4][4];
    #pragma unroll
    for (int rt = 0; rt < 4; ++rt)
        #pragma unroll
        for (int i = 0; i < 4; ++i) { bd[rt][i] = 3.4e38f; bi[rt][i] = 0; }

    #pragma unroll 1
    for (int ct = 0; ct < 16; ++ct) {
        bf16x8 B0[3], B1[3];
        const int off0 = (ct * 64 + l) * 8;
        B0[0] = *(const bf16x8*)&CB2[off0];
        B0[1] = *(const bf16x8*)&CB2[12288 + off0];
        B0[2] = *(const bf16x8*)&CB2[24576 + off0];
        if (l < 32) {
            const int off1 = 8192 + (ct * 32 + l) * 8;
            B1[0] = *(const bf16x8*)&CB2[off1];
            B1[1] = *(const bf16x8*)&CB2[12288 + off1];
            B1[2] = *(const bf16x8*)&CB2[24576 + off1];
        } else {
            B1[0] = bf8zero(); B1[1] = bf8zero(); B1[2] = bf8zero();
        }
        const float cnv = CN[ct * 16 + c16];
        const int idxbase = ct * 16 + c16;
        #pragma unroll
        for (int rt = 0; rt < 4; ++rt) {
            f32x4 a = (f32x4){0.f, 0.f, 0.f, 0.f};
            a = __builtin_amdgcn_mfma_f32_16x16x32_bf16(X0[rt][2], B0[0], a, 0, 0, 0);
            a = __builtin_amdgcn_mfma_f32_16x16x32_bf16(X0[rt][1], B0[1], a, 0, 0, 0);
            a = __builtin_amdgcn_mfma_f32_16x16x32_bf16(X0[rt][0], B0[2], a, 0, 0, 0);
            a = __builtin_amdgcn_mfma_f32_16x16x32_bf16(X1[rt][2], B1[0], a, 0, 0, 0);
            a = __builtin_amdgcn_mfma_f32_16x16x32_bf16(X1[rt][1], B1[1], a, 0, 0, 0);
            a = __builtin_amdgcn_mfma_f32_16x16x32_bf16(X1[rt][0], B1[2], a, 0, 0, 0);
            a = __builtin_amdgcn_mfma_f32_16x16x32_bf16(X0[rt][1], B0[0], a, 0, 0, 0);
            a = __builtin_amdgcn_mfma_f32_16x16x32_bf16(X0[rt][0], B0[1], a, 0, 0, 0);
            a = __builtin_amdgcn_mfma_f32_16x16x32_bf16(X1[rt][1], B1[0], a, 0, 0, 0);
            a = __builtin_amdgcn_mfma_f32_16x16x32_bf16(X1[rt][0], B1[1], a, 0, 0, 0);
            a = __builtin_amdgcn_mfma_f32_16x16x32_bf16(X0[rt][0], B0[0], a, 0, 0, 0);
            a = __builtin_amdgcn_mfma_f32_16x16x32_bf16(X1[rt][0], B1[0], a, 0, 0, 0);
            #pragma unroll
            for (int i = 0; i < 4; ++i) {
                float d = fmaf(-2.f, a[i], cnv);
                if (d < bd[rt][i]) { bd[rt][i] = d; bi[rt][i] = idxbase; }
            }
        }
    }

    float lm = 0.f;
    #pragma unroll
    for (int rt = 0; rt < 4; ++rt) {
        #pragma unroll
        for (int i = 0; i < 4; ++i) {
            float d = bd[rt][i]; int ix = bi[rt][i];
            #pragma unroll
            for (int m = 1; m < 16; m <<= 1) {
                float d2 = __shfl_xor(d, m, 64);
                int   i2 = __shfl_xor(ix, m, 64);
                if (d2 < d || (d2 == d && i2 < ix)) { d = d2; ix = i2; }
            }
            if (c16 == 0) {
                size_t row = rowbase + rt * 16 + 4 * g + i;
                out[2 * row + 1] = (float)(ix + KW);
                lm += d + 1.0f;      // ||xf||^2 == 1
            }
        }
    }
    #pragma unroll
    for (int m = 1; m < 64; m <<= 1) lm += __shfl_xor(lm, m, 64);
    if (l == 0) red4[w] = lm;
    __syncthreads();
    if (tid == 0) atomicAdd(&sums[1], red4[0] + red4[1] + red4[2] + red4[3]);
}

// LDS histogram over the produced encodings -> single global hist[1280].
__global__ __launch_bounds__(256) void hist_kernel(
    const float* __restrict__ out, int* __restrict__ hist)
{
    __shared__ int h[1280];
    const int tid = threadIdx.x;
    for (int i = tid; i < 1280; i += 256) h[i] = 0;
    __syncthreads();
    const int base = blockIdx.x * 4096;
    for (int rr = tid; rr < 4096; rr += 256) {
        const int r = base + rr;
        atomicAdd(&h[(int)out[2 * r]], 1);
        atomicAdd(&h[1024 + ((int)out[2 * r + 1] - KW)], 1);
    }
    __syncthreads();
    for (int i = tid; i < 1280; i += 256)
        if (h[i]) atomicAdd(&hist[i], h[i]);
}

__global__ __launch_bounds__(256) void finalize_kernel(
    const int* __restrict__ hist, const float* __restrict__ sums,
    float* __restrict__ out)
{
    __shared__ float red[4];
    const int tid = threadIdx.x;
    const bool wv = (blockIdx.x == 0);
    const int K = wv ? KW : KM;
    const int base = wv ? 0 : 1024;
    float s = 0.f;
    for (int i = tid; i < K; i += 256) {
        float p = (float)hist[base + i] * (1.0f / 65536.0f);
        s += p * logf(p + 1e-10f);
    }
    #pragma unroll
    for (int off = 32; off >= 1; off >>= 1) s += __shfl_xor(s, off, 64);
    if ((tid & 63) == 0) red[tid >> 6] = s;
    __syncthreads();
    if (tid == 0) {
        float t = red[0] + red[1] + red[2] + red[3];
        float ppl = expf(-t);
        float denom = wv ? (float)(NROWS * DW) : (float)(NROWS * DM);
        int obase = 2 * NROWS + (wv ? 0 : 2);
        out[obase]     = ppl;
        out[obase + 1] = 1.25f * sums[wv ? 0 : 1] / denom;
    }
}

extern "C" void kernel_launch(void* const* d_in, const int* in_sizes, int n_in,
                              void* d_out, int out_size, void* d_ws, size_t ws_size,
                              hipStream_t stream) {
    const float* X   = (const float*)d_in[0];
    const float* cbw = (const float*)d_in[1];
    const float* cbm = (const float*)d_in[2];
    float* out = (float*)d_out;

    char* ws = (char*)d_ws;
    float* sums   = (float*)(ws + WS_SUMS);
    int*   hist   = (int*)(ws + WS_HIST);
    float* cn_w   = (float*)(ws + WS_CNW);
    float* cn_m   = (float*)(ws + WS_CNM);
    float* costab = (float*)(ws + WS_COSTAB);
    short* ctf    = (short*)(ws + WS_CTF);
    short* cbf    = (short*)(ws + WS_CBF);

    prep_kernel<<<23, 256, 0, stream>>>(cbw, cbm, sums, hist, cn_w, cn_m, costab);
    prep2_kernel<<<63, 256, 0, stream>>>(costab, cbm, ctf, cbf);
    wave_vq_mfma<<<NROWS / 256, 256, 0, stream>>>(X, cbw, cn_w, out, sums);
    mfcc_mfma<<<NROWS / 256, 256, 0, stream>>>(X, cn_m, ctf, cbf, out, sums);
    hist_kernel<<<16, 256, 0, stream>>>(out, hist);
    finalize_kernel<<<2, 256, 0, stream>>>(hist, sums, out);
}

// Round 7
// 94.130 us; speedup vs baseline: 5.9944x; 1.1369x over previous
//
#include <hip/hip_runtime.h>
#include <hip/hip_bf16.h>
#include <math.h>

// ---------------------------------------------------------------------------
// AudioVQMix. Wave VQ = 2-term bf16-split MFMA GEMM, B pre-fragmented in
// prep -> kernel reads B direct from global (L2-resident, no LDS/barriers).
// mfcc = 3-term-split MFMA transform + f32 l2norm + 3-term-split MFMA VQ,
// tables likewise read direct from global. Losses from GEMM distances.
// Output (f32): [0..131071] encodings, then wave_ppl, wave_loss, mfcc_ppl,
// mfcc_loss.
// ---------------------------------------------------------------------------

#define NROWS 65536
#define DW    80
#define KW    1024
#define DM    38
#define KM    256

typedef __attribute__((ext_vector_type(8))) short bf16x8;
typedef __attribute__((ext_vector_type(4))) float f32x4;

__device__ __forceinline__ void bf16split(float v, short& h, short& l) {
    __hip_bfloat16 hb = __float2bfloat16(v);
    float hf = __bfloat162float(hb);
    __hip_bfloat16 lb = __float2bfloat16(v - hf);
    h = *(short*)&hb;
    l = *(short*)&lb;
}

__device__ __forceinline__ void bf16split3(float v, short& a, short& b, short& c) {
    __hip_bfloat16 h = __float2bfloat16(v);
    float hf = __bfloat162float(h);
    float r = v - hf;
    __hip_bfloat16 m = __float2bfloat16(r);
    float mf = __bfloat162float(m);
    __hip_bfloat16 lo = __float2bfloat16(r - mf);
    a = *(short*)&h; b = *(short*)&m; c = *(short*)&lo;
}

__device__ __forceinline__ bf16x8 bf8zero() {
    bf16x8 z;
    #pragma unroll
    for (int j = 0; j < 8; ++j) z[j] = 0;
    return z;
}

// workspace layout (bytes)
#define WS_SUMS   0        // 2 f32
#define WS_HIST   256      // 1280 i32 = 5120
#define WS_CNW    5376     // 1024 f32 = 4096
#define WS_CNM    9472     // 256 f32 = 1024
#define WS_CTF    10496    // 3 x 3840 shorts = 23040
#define WS_CBF    33536    // 3 x 12288 shorts = 73728
#define WS_CWH    107264   // 12288 frags x 8 shorts x 2B = 196608
#define WS_CWL    303872   // 196608  (end 500480)

// ---------------------------------------------------------------------------
// One prep kernel. Branch map (FIXED r6 bug: wave frag count is 12288, not
// 24576 — each idx writes BOTH hi and lo):
//   [0,12288)      wave codebook hi/lo fragments
//   [12288,16128)  mfcc cos-table 3-term fragments (3840)
//   [16128,28416)  mfcc codebook 3-term fragments (12288)
//   [28416,29440)  cn_w
//   [29440,29696)  cn_m
//   [29696,30976)  hist zero
//   30976,30977    sums zero
// Wave frag f: ct=f/192, s=(f%192)/64, l=f%64; code=ct*16+(l&15),
// k0=32s+8*(l>>4); zeros for k0>=80.
// ---------------------------------------------------------------------------
__global__ __launch_bounds__(256) void prep_kernel(
    const float* __restrict__ cbw, const float* __restrict__ cbm,
    float* __restrict__ sums, int* __restrict__ hist,
    float* __restrict__ cn_w, float* __restrict__ cn_m,
    short* __restrict__ ctf, short* __restrict__ cbf,
    short* __restrict__ cwh, short* __restrict__ cwl)
{
    int idx = blockIdx.x * 256 + threadIdx.x;
    if (idx < 12288) {
        const int f = idx;
        const int ct = f / 192, rem = f % 192, s = rem >> 6, l = rem & 63;
        const int code = ct * 16 + (l & 15);
        const int k0 = 32 * s + 8 * (l >> 4);
        bf16x8 h, lo;
        if (k0 < DW) {
            const float4* p = (const float4*)(cbw + (size_t)code * DW + k0);
            float4 u = p[0], v = p[1];
            float fv[8] = {u.x, u.y, u.z, u.w, v.x, v.y, v.z, v.w};
            #pragma unroll
            for (int j = 0; j < 8; ++j) {
                short hh, ll;
                bf16split(fv[j], hh, ll);
                h[j] = hh; lo[j] = ll;
            }
        } else { h = bf8zero(); lo = bf8zero(); }
        *(bf16x8*)&cwh[(size_t)f * 8] = h;
        *(bf16x8*)&cwl[(size_t)f * 8] = lo;
    } else if (idx < 16128) {
        int t = idx - 12288;
        int col, k;
        if (t < 3072) {
            int j = t & 7, l = (t >> 3) & 63, tt = t >> 9;
            col = (tt >> 1) * 16 + (l & 15);
            k = 32 * (tt & 1) + 8 * (l >> 4) + j;
        } else {
            int i2 = t - 3072;
            int j = i2 & 7, l = (i2 >> 3) & 31, ct = i2 >> 8;
            col = ct * 16 + (l & 15);
            k = 64 + 8 * (l >> 4) + j;
        }
        float v = (col < DM)
            ? (float)cos(2.0 * 3.14159265358979323846 * (double)((col + 2) * k) / 80.0)
            : 0.f;
        short a, b, c; bf16split3(v, a, b, c);
        ctf[t] = a; ctf[3840 + t] = b; ctf[7680 + t] = c;
    } else if (idx < 28416) {
        int i3 = idx - 16128;
        int code, k;
        if (i3 < 8192) {
            int j = i3 & 7, l = (i3 >> 3) & 63, ct = i3 >> 9;
            code = ct * 16 + (l & 15);
            k = 8 * (l >> 4) + j;
        } else {
            int i4 = i3 - 8192;
            int j = i4 & 7, l = (i4 >> 3) & 31, ct = i4 >> 8;
            code = ct * 16 + (l & 15);
            k = 32 + 8 * (l >> 4) + j;
        }
        float v = (k < DM) ? cbm[(size_t)code * DM + k] : 0.f;
        short a, b, c; bf16split3(v, a, b, c);
        cbf[i3] = a; cbf[12288 + i3] = b; cbf[24576 + i3] = c;
    } else if (idx < 29440) {
        int i = idx - 28416;
        const float* p = cbw + (size_t)i * DW;
        float s = 0.f;
        for (int k = 0; k < DW; ++k) s = fmaf(p[k], p[k], s);
        cn_w[i] = s;
    } else if (idx < 29696) {
        int i = idx - 29440;
        const float* p = cbm + (size_t)i * DM;
        float s = 0.f;
        for (int j = 0; j < DM; ++j) s = fmaf(p[j], p[j], s);
        cn_m[i] = s;
    } else if (idx < 30976) {
        hist[idx - 29696] = 0;
    } else if (idx == 30976) sums[0] = 0.f;
    else if (idx == 30977)   sums[1] = 0.f;
}

// ---------------------------------------------------------------------------
// Wave VQ via MFMA, B direct from global (pre-fragmented). No LDS, no
// barriers. MFMA sequence bit-identical to the r3/r5-verified kernel.
// ---------------------------------------------------------------------------
__global__ __launch_bounds__(256, 2) void wave_vq_mfma(
    const float* __restrict__ X, const short* __restrict__ cwh,
    const short* __restrict__ cwl, const float* __restrict__ cn,
    float* __restrict__ out, float* __restrict__ sums)
{
    __shared__ float redw[4];

    const int tid = threadIdx.x;
    const int l   = tid & 63;
    const int qu  = tid >> 6;
    const int c16 = l & 15;
    const int g   = l >> 4;
    const size_t rowbase = (size_t)blockIdx.x * 256 + (size_t)qu * 64;

    bf16x8 Ah[4][3], Al[4][3];
    float xs2[4] = {0.f, 0.f, 0.f, 0.f};
    #pragma unroll
    for (int rt = 0; rt < 4; ++rt) {
        #pragma unroll
        for (int s = 0; s < 3; ++s) {
            const int k0 = 32 * s + 8 * g;
            bf16x8 ah, al;
            if (k0 < DW) {
                const float4* ap =
                    (const float4*)(X + (rowbase + rt * 16 + c16) * DW + k0);
                float4 u = ap[0], w = ap[1];
                float f[8] = {u.x, u.y, u.z, u.w, w.x, w.y, w.z, w.w};
                #pragma unroll
                for (int j = 0; j < 8; ++j) {
                    short hh, ll;
                    bf16split(f[j], hh, ll);
                    ah[j] = hh; al[j] = ll;
                    xs2[rt] = fmaf(f[j], f[j], xs2[rt]);
                }
            } else {
                ah = bf8zero(); al = bf8zero();
            }
            Ah[rt][s] = ah; Al[rt][s] = al;
        }
    }
    #pragma unroll
    for (int rt = 0; rt < 4; ++rt) {
        xs2[rt] += __shfl_xor(xs2[rt], 16, 64);
        xs2[rt] += __shfl_xor(xs2[rt], 32, 64);
    }

    float bd[4][4];
    int   bi[4][4];
    #pragma unroll
    for (int rt = 0; rt < 4; ++rt)
        #pragma unroll
        for (int i = 0; i < 4; ++i) { bd[rt][i] = 3.4e38f; bi[rt][i] = 0; }

    const bf16x8* Hsrc = (const bf16x8*)cwh;
    const bf16x8* Lsrc = (const bf16x8*)cwl;

    // prefetch tile 0
    bf16x8 pbh[3], pbl[3];
    #pragma unroll
    for (int s = 0; s < 3; ++s) {
        pbh[s] = Hsrc[s * 64 + l];
        pbl[s] = Lsrc[s * 64 + l];
    }
    float pcn = cn[c16];

    #pragma unroll 1
    for (int ct = 0; ct < 64; ++ct) {
        bf16x8 bh[3], bl[3];
        #pragma unroll
        for (int s = 0; s < 3; ++s) { bh[s] = pbh[s]; bl[s] = pbl[s]; }
        const float cnv = pcn;
        if (ct < 63) {
            #pragma unroll
            for (int s = 0; s < 3; ++s) {
                pbh[s] = Hsrc[((ct + 1) * 3 + s) * 64 + l];
                pbl[s] = Lsrc[((ct + 1) * 3 + s) * 64 + l];
            }
            pcn = cn[(ct + 1) * 16 + c16];
        }

        f32x4 acc[4];
        #pragma unroll
        for (int rt = 0; rt < 4; ++rt) acc[rt] = (f32x4){0.f, 0.f, 0.f, 0.f};
        #pragma unroll
        for (int s = 0; s < 3; ++s) {
            #pragma unroll
            for (int rt = 0; rt < 4; ++rt)
                acc[rt] = __builtin_amdgcn_mfma_f32_16x16x32_bf16(Al[rt][s], bl[s], acc[rt], 0, 0, 0);
            #pragma unroll
            for (int rt = 0; rt < 4; ++rt)
                acc[rt] = __builtin_amdgcn_mfma_f32_16x16x32_bf16(Ah[rt][s], bl[s], acc[rt], 0, 0, 0);
            #pragma unroll
            for (int rt = 0; rt < 4; ++rt)
                acc[rt] = __builtin_amdgcn_mfma_f32_16x16x32_bf16(Al[rt][s], bh[s], acc[rt], 0, 0, 0);
            #pragma unroll
            for (int rt = 0; rt < 4; ++rt)
                acc[rt] = __builtin_amdgcn_mfma_f32_16x16x32_bf16(Ah[rt][s], bh[s], acc[rt], 0, 0, 0);
        }
        const int idxbase = ct * 16 + c16;
        #pragma unroll
        for (int rt = 0; rt < 4; ++rt) {
            #pragma unroll
            for (int i = 0; i < 4; ++i) {
                float d = fmaf(-2.f, acc[rt][i], cnv);
                if (d < bd[rt][i]) { bd[rt][i] = d; bi[rt][i] = idxbase; }
            }
        }
    }

    float lw = 0.f;
    #pragma unroll
    for (int rt = 0; rt < 4; ++rt) {
        #pragma unroll
        for (int i = 0; i < 4; ++i) {
            float d = bd[rt][i]; int ix = bi[rt][i];
            #pragma unroll
            for (int m = 1; m < 16; m <<= 1) {
                float d2 = __shfl_xor(d, m, 64);
                int   i2 = __shfl_xor(ix, m, 64);
                if (d2 < d || (d2 == d && i2 < ix)) { d = d2; ix = i2; }
            }
            float xn = __shfl(xs2[rt], (l & 48) + 4 * (l >> 4) + i, 64);
            if (c16 == 0) {
                size_t row = rowbase + rt * 16 + 4 * g + i;
                out[2 * row] = (float)ix;
                lw += d + xn;
            }
        }
    }
    #pragma unroll
    for (int m = 1; m < 64; m <<= 1) lw += __shfl_xor(lw, m, 64);
    if (l == 0) redw[qu] = lw;
    __syncthreads();
    if (tid == 0) atomicAdd(&sums[0], redw[0] + redw[1] + redw[2] + redw[3]);
}

// ---------------------------------------------------------------------------
// MFCC via MFMA, 3-term splits; cos/codebook fragments direct from global.
// Only XF (cross-lane exchange) + CN live in LDS.
// ---------------------------------------------------------------------------
__global__ __launch_bounds__(256, 2) void mfcc_mfma(
    const float* __restrict__ X, const float* __restrict__ cn_m,
    const short* __restrict__ ctf, const short* __restrict__ cbf,
    float* __restrict__ out, float* __restrict__ sums)
{
    __shared__ float XF[4][64 * 49];             // 50176 B
    __shared__ float CN[KM];
    __shared__ float red4[4];

    const int tid = threadIdx.x;
    const int l   = tid & 63;
    const int w   = tid >> 6;
    const int c16 = l & 15;
    const int g   = l >> 4;
    const size_t rowbase = (size_t)blockIdx.x * 256 + (size_t)w * 64;

    if (tid < KM) CN[tid] = cn_m[tid];
    __syncthreads();

    float* xfl = &XF[w][0];

    #pragma unroll 1
    for (int rt = 0; rt < 4; ++rt) {
        bf16x8 A0[3], A1[3], A2[3];
        #pragma unroll
        for (int s = 0; s < 3; ++s) {
            const int k0 = 32 * s + 8 * g;
            if (k0 < DW) {
                const float4* ap =
                    (const float4*)(X + (rowbase + rt * 16 + c16) * DW + k0);
                float4 u = ap[0], v = ap[1];
                float f[8] = {u.x, u.y, u.z, u.w, v.x, v.y, v.z, v.w};
                bf16x8 a0, a1, a2;
                #pragma unroll
                for (int j = 0; j < 8; ++j) {
                    short aa, bb, cc;
                    bf16split3(f[j], aa, bb, cc);
                    a0[j] = aa; a1[j] = bb; a2[j] = cc;
                }
                A0[s] = a0; A1[s] = a1; A2[s] = a2;
            } else {
                A0[s] = bf8zero(); A1[s] = bf8zero(); A2[s] = bf8zero();
            }
        }

        f32x4 acc[3];
        #pragma unroll
        for (int ct = 0; ct < 3; ++ct) acc[ct] = (f32x4){0.f, 0.f, 0.f, 0.f};

        #pragma unroll
        for (int s = 0; s < 3; ++s) {
            #pragma unroll
            for (int ct = 0; ct < 3; ++ct) {
                bf16x8 b0, b1, b2;
                if (s < 2) {
                    const int off = ((ct * 2 + s) * 64 + l) * 8;
                    b0 = *(const bf16x8*)&ctf[off];
                    b1 = *(const bf16x8*)&ctf[3840 + off];
                    b2 = *(const bf16x8*)&ctf[7680 + off];
                } else if (l < 32) {
                    const int off = 3072 + (ct * 32 + l) * 8;
                    b0 = *(const bf16x8*)&ctf[off];
                    b1 = *(const bf16x8*)&ctf[3840 + off];
                    b2 = *(const bf16x8*)&ctf[7680 + off];
                } else {
                    b0 = bf8zero(); b1 = bf8zero(); b2 = bf8zero();
                }
                acc[ct] = __builtin_amdgcn_mfma_f32_16x16x32_bf16(A2[s], b0, acc[ct], 0, 0, 0);
                acc[ct] = __builtin_amdgcn_mfma_f32_16x16x32_bf16(A1[s], b1, acc[ct], 0, 0, 0);
                acc[ct] = __builtin_amdgcn_mfma_f32_16x16x32_bf16(A0[s], b2, acc[ct], 0, 0, 0);
                acc[ct] = __builtin_amdgcn_mfma_f32_16x16x32_bf16(A1[s], b0, acc[ct], 0, 0, 0);
                acc[ct] = __builtin_amdgcn_mfma_f32_16x16x32_bf16(A0[s], b1, acc[ct], 0, 0, 0);
                acc[ct] = __builtin_amdgcn_mfma_f32_16x16x32_bf16(A0[s], b0, acc[ct], 0, 0, 0);
            }
        }

        #pragma unroll
        for (int i = 0; i < 4; ++i) {
            float n2 = acc[0][i] * acc[0][i];
            n2 = fmaf(acc[1][i], acc[1][i], n2);
            n2 = fmaf(acc[2][i], acc[2][i], n2);
            #pragma unroll
            for (int m = 1; m < 16; m <<= 1) n2 += __shfl_xor(n2, m, 64);
            float inv = 1.0f / fmaxf(sqrtf(n2), 1e-12f);
            const int row_l = rt * 16 + 4 * g + i;
            #pragma unroll
            for (int ct = 0; ct < 3; ++ct)
                xfl[row_l * 49 + ct * 16 + c16] = acc[ct][i] * inv;
        }
    }
    __syncthreads();

    bf16x8 X0[4][3], X1[4][3];
    #pragma unroll
    for (int rt = 0; rt < 4; ++rt) {
        const int r0 = rt * 16 + c16;
        {
            const float* p = &xfl[r0 * 49 + 8 * g];
            bf16x8 q0, q1, q2;
            #pragma unroll
            for (int j = 0; j < 8; ++j) {
                short aa, bb, cc;
                bf16split3(p[j], aa, bb, cc);
                q0[j] = aa; q1[j] = bb; q2[j] = cc;
            }
            X0[rt][0] = q0; X0[rt][1] = q1; X0[rt][2] = q2;
        }
        if (g < 2) {
            const float* p = &xfl[r0 * 49 + 32 + 8 * g];
            bf16x8 q0, q1, q2;
            #pragma unroll
            for (int j = 0; j < 8; ++j) {
                short aa, bb, cc;
                bf16split3(p[j], aa, bb, cc);
                q0[j] = aa; q1[j] = bb; q2[j] = cc;
            }
            X1[rt][0] = q0; X1[rt][1] = q1; X1[rt][2] = q2;
        } else {
            X1[rt][0] = bf8zero(); X1[rt][1] = bf8zero(); X1[rt][2] = bf8zero();
        }
    }

    float bd[4][4];
    int   bi[4][4];
    #pragma unroll
    for (int rt = 0; rt < 4; ++rt)
        #pragma unroll
        for (int i = 0; i < 4; ++i) { bd[rt][i] = 3.4e38f; bi[rt][i] = 0; }

    #pragma unroll 1
    for (int ct = 0; ct < 16; ++ct) {
        bf16x8 B0[3], B1[3];
        const int off0 = (ct * 64 + l) * 8;
        B0[0] = *(const bf16x8*)&cbf[off0];
        B0[1] = *(const bf16x8*)&cbf[12288 + off0];
        B0[2] = *(const bf16x8*)&cbf[24576 + off0];
        if (l < 32) {
            const int off1 = 8192 + (ct * 32 + l) * 8;
            B1[0] = *(const bf16x8*)&cbf[off1];
            B1[1] = *(const bf16x8*)&cbf[12288 + off1];
            B1[2] = *(const bf16x8*)&cbf[24576 + off1];
        } else {
            B1[0] = bf8zero(); B1[1] = bf8zero(); B1[2] = bf8zero();
        }
        const float cnv = CN[ct * 16 + c16];
        const int idxbase = ct * 16 + c16;
        #pragma unroll
        for (int rt = 0; rt < 4; ++rt) {
            f32x4 a = (f32x4){0.f, 0.f, 0.f, 0.f};
            a = __builtin_amdgcn_mfma_f32_16x16x32_bf16(X0[rt][2], B0[0], a, 0, 0, 0);
            a = __builtin_amdgcn_mfma_f32_16x16x32_bf16(X0[rt][1], B0[1], a, 0, 0, 0);
            a = __builtin_amdgcn_mfma_f32_16x16x32_bf16(X0[rt][0], B0[2], a, 0, 0, 0);
            a = __builtin_amdgcn_mfma_f32_16x16x32_bf16(X1[rt][2], B1[0], a, 0, 0, 0);
            a = __builtin_amdgcn_mfma_f32_16x16x32_bf16(X1[rt][1], B1[1], a, 0, 0, 0);
            a = __builtin_amdgcn_mfma_f32_16x16x32_bf16(X1[rt][0], B1[2], a, 0, 0, 0);
            a = __builtin_amdgcn_mfma_f32_16x16x32_bf16(X0[rt][1], B0[0], a, 0, 0, 0);
            a = __builtin_amdgcn_mfma_f32_16x16x32_bf16(X0[rt][0], B0[1], a, 0, 0, 0);
            a = __builtin_amdgcn_mfma_f32_16x16x32_bf16(X1[rt][1], B1[0], a, 0, 0, 0);
            a = __builtin_amdgcn_mfma_f32_16x16x32_bf16(X1[rt][0], B1[1], a, 0, 0, 0);
            a = __builtin_amdgcn_mfma_f32_16x16x32_bf16(X0[rt][0], B0[0], a, 0, 0, 0);
            a = __builtin_amdgcn_mfma_f32_16x16x32_bf16(X1[rt][0], B1[0], a, 0, 0, 0);
            #pragma unroll
            for (int i = 0; i < 4; ++i) {
                float d = fmaf(-2.f, a[i], cnv);
                if (d < bd[rt][i]) { bd[rt][i] = d; bi[rt][i] = idxbase; }
            }
        }
    }

    float lm = 0.f;
    #pragma unroll
    for (int rt = 0; rt < 4; ++rt) {
        #pragma unroll
        for (int i = 0; i < 4; ++i) {
            float d = bd[rt][i]; int ix = bi[rt][i];
            #pragma unroll
            for (int m = 1; m < 16; m <<= 1) {
                float d2 = __shfl_xor(d, m, 64);
                int   i2 = __shfl_xor(ix, m, 64);
                if (d2 < d || (d2 == d && i2 < ix)) { d = d2; ix = i2; }
            }
            if (c16 == 0) {
                size_t row = rowbase + rt * 16 + 4 * g + i;
                out[2 * row + 1] = (float)(ix + KW);
                lm += d + 1.0f;      // ||xf||^2 == 1
            }
        }
    }
    #pragma unroll
    for (int m = 1; m < 64; m <<= 1) lm += __shfl_xor(lm, m, 64);
    if (l == 0) red4[w] = lm;
    __syncthreads();
    if (tid == 0) atomicAdd(&sums[1], red4[0] + red4[1] + red4[2] + red4[3]);
}

// LDS histogram over the produced encodings -> global hist[1280].
__global__ __launch_bounds__(256) void hist_kernel(
    const float* __restrict__ out, int* __restrict__ hist)
{
    __shared__ int h[1280];
    const int tid = threadIdx.x;
    for (int i = tid; i < 1280; i += 256) h[i] = 0;
    __syncthreads();
    const int base = blockIdx.x * 1024;
    for (int rr = tid; rr < 1024; rr += 256) {
        const int r = base + rr;
        atomicAdd(&h[(int)out[2 * r]], 1);
        atomicAdd(&h[1024 + ((int)out[2 * r + 1] - KW)], 1);
    }
    __syncthreads();
    for (int i = tid; i < 1280; i += 256)
        if (h[i]) atomicAdd(&hist[i], h[i]);
}

__global__ __launch_bounds__(256) void finalize_kernel(
    const int* __restrict__ hist, const float* __restrict__ sums,
    float* __restrict__ out)
{
    __shared__ float red[4];
    const int tid = threadIdx.x;
    const bool wv = (blockIdx.x == 0);
    const int K = wv ? KW : KM;
    const int base = wv ? 0 : 1024;
    float s = 0.f;
    for (int i = tid; i < K; i += 256) {
        float p = (float)hist[base + i] * (1.0f / 65536.0f);
        s += p * logf(p + 1e-10f);
    }
    #pragma unroll
    for (int off = 32; off >= 1; off >>= 1) s += __shfl_xor(s, off, 64);
    if ((tid & 63) == 0) red[tid >> 6] = s;
    __syncthreads();
    if (tid == 0) {
        float t = red[0] + red[1] + red[2] + red[3];
        float ppl = expf(-t);
        float denom = wv ? (float)(NROWS * DW) : (float)(NROWS * DM);
        int obase = 2 * NROWS + (wv ? 0 : 2);
        out[obase]     = ppl;
        out[obase + 1] = 1.25f * sums[wv ? 0 : 1] / denom;
    }
}

extern "C" void kernel_launch(void* const* d_in, const int* in_sizes, int n_in,
                              void* d_out, int out_size, void* d_ws, size_t ws_size,
                              hipStream_t stream) {
    const float* X   = (const float*)d_in[0];
    const float* cbw = (const float*)d_in[1];
    const float* cbm = (const float*)d_in[2];
    float* out = (float*)d_out;

    char* ws = (char*)d_ws;
    float* sums = (float*)(ws + WS_SUMS);
    int*   hist = (int*)(ws + WS_HIST);
    float* cn_w = (float*)(ws + WS_CNW);
    float* cn_m = (float*)(ws + WS_CNM);
    short* ctf  = (short*)(ws + WS_CTF);
    short* cbf  = (short*)(ws + WS_CBF);
    short* cwh  = (short*)(ws + WS_CWH);
    short* cwl  = (short*)(ws + WS_CWL);

    prep_kernel<<<122, 256, 0, stream>>>(cbw, cbm, sums, hist, cn_w, cn_m,
                                         ctf, cbf, cwh, cwl);
    wave_vq_mfma<<<NROWS / 256, 256, 0, stream>>>(X, cwh, cwl, cn_w, out, sums);
    mfcc_mfma<<<NROWS / 256, 256, 0, stream>>>(X, cn_m, ctf, cbf, out, sums);
    hist_kernel<<<64, 256, 0, stream>>>(out, hist);
    finalize_kernel<<<2, 256, 0, stream>>>(hist, sums, out);
}

// Round 8
// 89.725 us; speedup vs baseline: 6.2887x; 1.0491x over previous
//
#include <hip/hip_runtime.h>
#include <hip/hip_bf16.h>
#include <math.h>

// ---------------------------------------------------------------------------
// AudioVQMix. Wave VQ = 2-term bf16-split MFMA GEMM, B pre-fragmented in
// prep -> kernel reads B direct from global (L2-resident). Occupancy via
// code-split: wave pair shares a 64-row group, each wave scans half the
// codebook, exact (d,idx) combine in LDS. mfcc = 3-term-split MFMA
// transform + f32 l2norm + 3-term-split MFMA VQ, same code-split.
// Output (f32): [0..131071] encodings, then wave_ppl, wave_loss, mfcc_ppl,
// mfcc_loss.
// ---------------------------------------------------------------------------

#define NROWS 65536
#define DW    80
#define KW    1024
#define DM    38
#define KM    256

typedef __attribute__((ext_vector_type(8))) short bf16x8;
typedef __attribute__((ext_vector_type(4))) float f32x4;

__device__ __forceinline__ void bf16split(float v, short& h, short& l) {
    __hip_bfloat16 hb = __float2bfloat16(v);
    float hf = __bfloat162float(hb);
    __hip_bfloat16 lb = __float2bfloat16(v - hf);
    h = *(short*)&hb;
    l = *(short*)&lb;
}

__device__ __forceinline__ void bf16split3(float v, short& a, short& b, short& c) {
    __hip_bfloat16 h = __float2bfloat16(v);
    float hf = __bfloat162float(h);
    float r = v - hf;
    __hip_bfloat16 m = __float2bfloat16(r);
    float mf = __bfloat162float(m);
    __hip_bfloat16 lo = __float2bfloat16(r - mf);
    a = *(short*)&h; b = *(short*)&m; c = *(short*)&lo;
}

__device__ __forceinline__ bf16x8 bf8zero() {
    bf16x8 z;
    #pragma unroll
    for (int j = 0; j < 8; ++j) z[j] = 0;
    return z;
}

// workspace layout (bytes)
#define WS_SUMS   0        // 2 f32
#define WS_HIST   256      // 1280 i32 = 5120
#define WS_CNW    5376     // 1024 f32 = 4096
#define WS_CNM    9472     // 256 f32 = 1024
#define WS_CTF    10496    // 3 x 3840 shorts = 23040
#define WS_CBF    33536    // 3 x 12288 shorts = 73728
#define WS_CWH    107264   // 12288 frags x 8 shorts x 2B = 196608
#define WS_CWL    303872   // 196608  (end 500480)

// ---------------------------------------------------------------------------
// Prep (r7-verified). Branch map:
//   [0,12288) wave frags | [12288,16128) cos frags | [16128,28416) cbm frags
//   [28416,29440) cn_w | [29440,29696) cn_m | [29696,30976) hist | 30976/7 sums
// ---------------------------------------------------------------------------
__global__ __launch_bounds__(256) void prep_kernel(
    const float* __restrict__ cbw, const float* __restrict__ cbm,
    float* __restrict__ sums, int* __restrict__ hist,
    float* __restrict__ cn_w, float* __restrict__ cn_m,
    short* __restrict__ ctf, short* __restrict__ cbf,
    short* __restrict__ cwh, short* __restrict__ cwl)
{
    int idx = blockIdx.x * 256 + threadIdx.x;
    if (idx < 12288) {
        const int f = idx;
        const int ct = f / 192, rem = f % 192, s = rem >> 6, l = rem & 63;
        const int code = ct * 16 + (l & 15);
        const int k0 = 32 * s + 8 * (l >> 4);
        bf16x8 h, lo;
        if (k0 < DW) {
            const float4* p = (const float4*)(cbw + (size_t)code * DW + k0);
            float4 u = p[0], v = p[1];
            float fv[8] = {u.x, u.y, u.z, u.w, v.x, v.y, v.z, v.w};
            #pragma unroll
            for (int j = 0; j < 8; ++j) {
                short hh, ll;
                bf16split(fv[j], hh, ll);
                h[j] = hh; lo[j] = ll;
            }
        } else { h = bf8zero(); lo = bf8zero(); }
        *(bf16x8*)&cwh[(size_t)f * 8] = h;
        *(bf16x8*)&cwl[(size_t)f * 8] = lo;
    } else if (idx < 16128) {
        int t = idx - 12288;
        int col, k;
        if (t < 3072) {
            int j = t & 7, l = (t >> 3) & 63, tt = t >> 9;
            col = (tt >> 1) * 16 + (l & 15);
            k = 32 * (tt & 1) + 8 * (l >> 4) + j;
        } else {
            int i2 = t - 3072;
            int j = i2 & 7, l = (i2 >> 3) & 31, ct = i2 >> 8;
            col = ct * 16 + (l & 15);
            k = 64 + 8 * (l >> 4) + j;
        }
        float v = (col < DM)
            ? (float)cos(2.0 * 3.14159265358979323846 * (double)((col + 2) * k) / 80.0)
            : 0.f;
        short a, b, c; bf16split3(v, a, b, c);
        ctf[t] = a; ctf[3840 + t] = b; ctf[7680 + t] = c;
    } else if (idx < 28416) {
        int i3 = idx - 16128;
        int code, k;
        if (i3 < 8192) {
            int j = i3 & 7, l = (i3 >> 3) & 63, ct = i3 >> 9;
            code = ct * 16 + (l & 15);
            k = 8 * (l >> 4) + j;
        } else {
            int i4 = i3 - 8192;
            int j = i4 & 7, l = (i4 >> 3) & 31, ct = i4 >> 8;
            code = ct * 16 + (l & 15);
            k = 32 + 8 * (l >> 4) + j;
        }
        float v = (k < DM) ? cbm[(size_t)code * DM + k] : 0.f;
        short a, b, c; bf16split3(v, a, b, c);
        cbf[i3] = a; cbf[12288 + i3] = b; cbf[24576 + i3] = c;
    } else if (idx < 29440) {
        int i = idx - 28416;
        const float* p = cbw + (size_t)i * DW;
        float s = 0.f;
        for (int k = 0; k < DW; ++k) s = fmaf(p[k], p[k], s);
        cn_w[i] = s;
    } else if (idx < 29696) {
        int i = idx - 29440;
        const float* p = cbm + (size_t)i * DM;
        float s = 0.f;
        for (int j = 0; j < DM; ++j) s = fmaf(p[j], p[j], s);
        cn_m[i] = s;
    } else if (idx < 30976) {
        hist[idx - 29696] = 0;
    } else if (idx == 30976) sums[0] = 0.f;
    else if (idx == 30977)   sums[1] = 0.f;
}

// ---------------------------------------------------------------------------
// Wave VQ. Block = 4 waves / 128 rows. Waves (2g, 2g+1) share row group g;
// wave half h scans codes [h*512, h*512+512). Exact cross-wave combine.
// ---------------------------------------------------------------------------
__global__ __launch_bounds__(256, 2) void wave_vq_mfma(
    const float* __restrict__ X, const short* __restrict__ cwh,
    const short* __restrict__ cwl, const float* __restrict__ cn,
    float* __restrict__ out, float* __restrict__ sums)
{
    __shared__ float sd[2][64][16];
    __shared__ int   si[2][64][16];
    __shared__ float redw[2];

    const int tid  = threadIdx.x;
    const int l    = tid & 63;
    const int qu   = tid >> 6;
    const int grp  = qu >> 1;
    const int half = qu & 1;
    const int c16  = l & 15;
    const int g    = l >> 4;
    const size_t rowbase = (size_t)blockIdx.x * 128 + (size_t)grp * 64;

    bf16x8 Ah[4][3], Al[4][3];
    float xs2[4] = {0.f, 0.f, 0.f, 0.f};
    #pragma unroll
    for (int rt = 0; rt < 4; ++rt) {
        #pragma unroll
        for (int s = 0; s < 3; ++s) {
            const int k0 = 32 * s + 8 * g;
            bf16x8 ah, al;
            if (k0 < DW) {
                const float4* ap =
                    (const float4*)(X + (rowbase + rt * 16 + c16) * DW + k0);
                float4 u = ap[0], w = ap[1];
                float f[8] = {u.x, u.y, u.z, u.w, w.x, w.y, w.z, w.w};
                #pragma unroll
                for (int j = 0; j < 8; ++j) {
                    short hh, ll;
                    bf16split(f[j], hh, ll);
                    ah[j] = hh; al[j] = ll;
                    xs2[rt] = fmaf(f[j], f[j], xs2[rt]);
                }
            } else {
                ah = bf8zero(); al = bf8zero();
            }
            Ah[rt][s] = ah; Al[rt][s] = al;
        }
    }
    #pragma unroll
    for (int rt = 0; rt < 4; ++rt) {
        xs2[rt] += __shfl_xor(xs2[rt], 16, 64);
        xs2[rt] += __shfl_xor(xs2[rt], 32, 64);
    }

    float bd[4][4];
    int   bi[4][4];
    #pragma unroll
    for (int rt = 0; rt < 4; ++rt)
        #pragma unroll
        for (int i = 0; i < 4; ++i) { bd[rt][i] = 3.4e38f; bi[rt][i] = 0; }

    const bf16x8* Hsrc = (const bf16x8*)cwh;
    const bf16x8* Lsrc = (const bf16x8*)cwl;
    const int ct0 = half * 32;

    // prefetch first tile of this half
    bf16x8 pbh[3], pbl[3];
    #pragma unroll
    for (int s = 0; s < 3; ++s) {
        pbh[s] = Hsrc[(ct0 * 3 + s) * 64 + l];
        pbl[s] = Lsrc[(ct0 * 3 + s) * 64 + l];
    }
    float pcn = cn[ct0 * 16 + c16];

    #pragma unroll 1
    for (int ctl = 0; ctl < 32; ++ctl) {
        const int ct = ct0 + ctl;
        bf16x8 bh[3], bl[3];
        #pragma unroll
        for (int s = 0; s < 3; ++s) { bh[s] = pbh[s]; bl[s] = pbl[s]; }
        const float cnv = pcn;
        if (ctl < 31) {
            #pragma unroll
            for (int s = 0; s < 3; ++s) {
                pbh[s] = Hsrc[((ct + 1) * 3 + s) * 64 + l];
                pbl[s] = Lsrc[((ct + 1) * 3 + s) * 64 + l];
            }
            pcn = cn[(ct + 1) * 16 + c16];
        }

        f32x4 acc[4];
        #pragma unroll
        for (int rt = 0; rt < 4; ++rt) acc[rt] = (f32x4){0.f, 0.f, 0.f, 0.f};
        #pragma unroll
        for (int s = 0; s < 3; ++s) {
            #pragma unroll
            for (int rt = 0; rt < 4; ++rt)
                acc[rt] = __builtin_amdgcn_mfma_f32_16x16x32_bf16(Al[rt][s], bl[s], acc[rt], 0, 0, 0);
            #pragma unroll
            for (int rt = 0; rt < 4; ++rt)
                acc[rt] = __builtin_amdgcn_mfma_f32_16x16x32_bf16(Ah[rt][s], bl[s], acc[rt], 0, 0, 0);
            #pragma unroll
            for (int rt = 0; rt < 4; ++rt)
                acc[rt] = __builtin_amdgcn_mfma_f32_16x16x32_bf16(Al[rt][s], bh[s], acc[rt], 0, 0, 0);
            #pragma unroll
            for (int rt = 0; rt < 4; ++rt)
                acc[rt] = __builtin_amdgcn_mfma_f32_16x16x32_bf16(Ah[rt][s], bh[s], acc[rt], 0, 0, 0);
        }
        const int idxbase = ct * 16 + c16;
        #pragma unroll
        for (int rt = 0; rt < 4; ++rt) {
            #pragma unroll
            for (int i = 0; i < 4; ++i) {
                float d = fmaf(-2.f, acc[rt][i], cnv);
                if (d < bd[rt][i]) { bd[rt][i] = d; bi[rt][i] = idxbase; }
            }
        }
    }

    // cross-wave combine: odd half publishes, even half merges (ties -> lower
    // index; odd half's indices are all >= 512 so even wins ties naturally).
    if (half == 1) {
        #pragma unroll
        for (int rt = 0; rt < 4; ++rt)
            #pragma unroll
            for (int i = 0; i < 4; ++i) {
                sd[grp][l][rt * 4 + i] = bd[rt][i];
                si[grp][l][rt * 4 + i] = bi[rt][i];
            }
    }
    __syncthreads();
    if (half == 0) {
        float lw = 0.f;
        #pragma unroll
        for (int rt = 0; rt < 4; ++rt) {
            #pragma unroll
            for (int i = 0; i < 4; ++i) {
                float d = bd[rt][i]; int ix = bi[rt][i];
                float dp = sd[grp][l][rt * 4 + i];
                int   ip = si[grp][l][rt * 4 + i];
                if (dp < d || (dp == d && ip < ix)) { d = dp; ix = ip; }
                #pragma unroll
                for (int m = 1; m < 16; m <<= 1) {
                    float d2 = __shfl_xor(d, m, 64);
                    int   i2 = __shfl_xor(ix, m, 64);
                    if (d2 < d || (d2 == d && i2 < ix)) { d = d2; ix = i2; }
                }
                float xn = __shfl(xs2[rt], (l & 48) + 4 * (l >> 4) + i, 64);
                if (c16 == 0) {
                    size_t row = rowbase + rt * 16 + 4 * g + i;
                    out[2 * row] = (float)ix;
                    lw += d + xn;
                }
            }
        }
        #pragma unroll
        for (int m = 1; m < 64; m <<= 1) lw += __shfl_xor(lw, m, 64);
        if (l == 0) redw[grp] = lw;
    }
    __syncthreads();
    if (tid == 0) atomicAdd(&sums[0], redw[0] + redw[1]);
}

// ---------------------------------------------------------------------------
// MFCC. Block = 4 waves / 128 rows. Wave pair (2g, 2g+1) shares row group g:
// transform rt-tiles split (wave half h does rt = 2h, 2h+1), VQ codes split
// (half h scans ct [8h, 8h+8)). Cross-wave combine as in wave kernel.
// ---------------------------------------------------------------------------
__global__ __launch_bounds__(256, 2) void mfcc_mfma(
    const float* __restrict__ X, const float* __restrict__ cn_m,
    const short* __restrict__ ctf, const short* __restrict__ cbf,
    float* __restrict__ out, float* __restrict__ sums)
{
    __shared__ float XF[2][64 * 49];             // 25088 B
    __shared__ float sd[2][64][16];
    __shared__ int   si[2][64][16];
    __shared__ float CN[KM];
    __shared__ float red2[2];

    const int tid  = threadIdx.x;
    const int l    = tid & 63;
    const int qu   = tid >> 6;
    const int grp  = qu >> 1;
    const int half = qu & 1;
    const int c16  = l & 15;
    const int g    = l >> 4;
    const size_t rowbase = (size_t)blockIdx.x * 128 + (size_t)grp * 64;

    if (tid < KM) CN[tid] = cn_m[tid];

    float* xfl = &XF[grp][0];

    // ---- transform: this wave's 2 rt-tiles ----
    #pragma unroll 1
    for (int rt2 = 0; rt2 < 2; ++rt2) {
        const int rt = half * 2 + rt2;
        bf16x8 A0[3], A1[3], A2[3];
        #pragma unroll
        for (int s = 0; s < 3; ++s) {
            const int k0 = 32 * s + 8 * g;
            if (k0 < DW) {
                const float4* ap =
                    (const float4*)(X + (rowbase + rt * 16 + c16) * DW + k0);
                float4 u = ap[0], v = ap[1];
                float f[8] = {u.x, u.y, u.z, u.w, v.x, v.y, v.z, v.w};
                bf16x8 a0, a1, a2;
                #pragma unroll
                for (int j = 0; j < 8; ++j) {
                    short aa, bb, cc;
                    bf16split3(f[j], aa, bb, cc);
                    a0[j] = aa; a1[j] = bb; a2[j] = cc;
                }
                A0[s] = a0; A1[s] = a1; A2[s] = a2;
            } else {
                A0[s] = bf8zero(); A1[s] = bf8zero(); A2[s] = bf8zero();
            }
        }

        f32x4 acc[3];
        #pragma unroll
        for (int ct = 0; ct < 3; ++ct) acc[ct] = (f32x4){0.f, 0.f, 0.f, 0.f};

        #pragma unroll
        for (int s = 0; s < 3; ++s) {
            #pragma unroll
            for (int ct = 0; ct < 3; ++ct) {
                bf16x8 b0, b1, b2;
                if (s < 2) {
                    const int off = ((ct * 2 + s) * 64 + l) * 8;
                    b0 = *(const bf16x8*)&ctf[off];
                    b1 = *(const bf16x8*)&ctf[3840 + off];
                    b2 = *(const bf16x8*)&ctf[7680 + off];
                } else if (l < 32) {
                    const int off = 3072 + (ct * 32 + l) * 8;
                    b0 = *(const bf16x8*)&ctf[off];
                    b1 = *(const bf16x8*)&ctf[3840 + off];
                    b2 = *(const bf16x8*)&ctf[7680 + off];
                } else {
                    b0 = bf8zero(); b1 = bf8zero(); b2 = bf8zero();
                }
                acc[ct] = __builtin_amdgcn_mfma_f32_16x16x32_bf16(A2[s], b0, acc[ct], 0, 0, 0);
                acc[ct] = __builtin_amdgcn_mfma_f32_16x16x32_bf16(A1[s], b1, acc[ct], 0, 0, 0);
                acc[ct] = __builtin_amdgcn_mfma_f32_16x16x32_bf16(A0[s], b2, acc[ct], 0, 0, 0);
                acc[ct] = __builtin_amdgcn_mfma_f32_16x16x32_bf16(A1[s], b0, acc[ct], 0, 0, 0);
                acc[ct] = __builtin_amdgcn_mfma_f32_16x16x32_bf16(A0[s], b1, acc[ct], 0, 0, 0);
                acc[ct] = __builtin_amdgcn_mfma_f32_16x16x32_bf16(A0[s], b0, acc[ct], 0, 0, 0);
            }
        }

        #pragma unroll
        for (int i = 0; i < 4; ++i) {
            float n2 = acc[0][i] * acc[0][i];
            n2 = fmaf(acc[1][i], acc[1][i], n2);
            n2 = fmaf(acc[2][i], acc[2][i], n2);
            #pragma unroll
            for (int m = 1; m < 16; m <<= 1) n2 += __shfl_xor(n2, m, 64);
            float inv = 1.0f / fmaxf(sqrtf(n2), 1e-12f);
            const int row_l = rt * 16 + 4 * g + i;
            #pragma unroll
            for (int ct = 0; ct < 3; ++ct)
                xfl[row_l * 49 + ct * 16 + c16] = acc[ct][i] * inv;
        }
    }
    __syncthreads();

    // ---- VQ A-frags: re-split xf (f32-exact) into 3 bf16 terms ----
    bf16x8 X0[4][3], X1[4][3];
    #pragma unroll
    for (int rt = 0; rt < 4; ++rt) {
        const int r0 = rt * 16 + c16;
        {
            const float* p = &xfl[r0 * 49 + 8 * g];
            bf16x8 q0, q1, q2;
            #pragma unroll
            for (int j = 0; j < 8; ++j) {
                short aa, bb, cc;
                bf16split3(p[j], aa, bb, cc);
                q0[j] = aa; q1[j] = bb; q2[j] = cc;
            }
            X0[rt][0] = q0; X0[rt][1] = q1; X0[rt][2] = q2;
        }
        if (g < 2) {
            const float* p = &xfl[r0 * 49 + 32 + 8 * g];
            bf16x8 q0, q1, q2;
            #pragma unroll
            for (int j = 0; j < 8; ++j) {
                short aa, bb, cc;
                bf16split3(p[j], aa, bb, cc);
                q0[j] = aa; q1[j] = bb; q2[j] = cc;
            }
            X1[rt][0] = q0; X1[rt][1] = q1; X1[rt][2] = q2;
        } else {
            X1[rt][0] = bf8zero(); X1[rt][1] = bf8zero(); X1[rt][2] = bf8zero();
        }
    }

    float bd[4][4];
    int   bi[4][4];
    #pragma unroll
    for (int rt = 0; rt < 4; ++rt)
        #pragma unroll
        for (int i = 0; i < 4; ++i) { bd[rt][i] = 3.4e38f; bi[rt][i] = 0; }

    #pragma unroll 1
    for (int ctl = 0; ctl < 8; ++ctl) {
        const int ct = half * 8 + ctl;
        bf16x8 B0[3], B1[3];
        const int off0 = (ct * 64 + l) * 8;
        B0[0] = *(const bf16x8*)&cbf[off0];
        B0[1] = *(const bf16x8*)&cbf[12288 + off0];
        B0[2] = *(const bf16x8*)&cbf[24576 + off0];
        if (l < 32) {
            const int off1 = 8192 + (ct * 32 + l) * 8;
            B1[0] = *(const bf16x8*)&cbf[off1];
            B1[1] = *(const bf16x8*)&cbf[12288 + off1];
            B1[2] = *(const bf16x8*)&cbf[24576 + off1];
        } else {
            B1[0] = bf8zero(); B1[1] = bf8zero(); B1[2] = bf8zero();
        }
        const float cnv = CN[ct * 16 + c16];
        const int idxbase = ct * 16 + c16;
        #pragma unroll
        for (int rt = 0; rt < 4; ++rt) {
            f32x4 a = (f32x4){0.f, 0.f, 0.f, 0.f};
            a = __builtin_amdgcn_mfma_f32_16x16x32_bf16(X0[rt][2], B0[0], a, 0, 0, 0);
            a = __builtin_amdgcn_mfma_f32_16x16x32_bf16(X0[rt][1], B0[1], a, 0, 0, 0);
            a = __builtin_amdgcn_mfma_f32_16x16x32_bf16(X0[rt][0], B0[2], a, 0, 0, 0);
            a = __builtin_amdgcn_mfma_f32_16x16x32_bf16(X1[rt][2], B1[0], a, 0, 0, 0);
            a = __builtin_amdgcn_mfma_f32_16x16x32_bf16(X1[rt][1], B1[1], a, 0, 0, 0);
            a = __builtin_amdgcn_mfma_f32_16x16x32_bf16(X1[rt][0], B1[2], a, 0, 0, 0);
            a = __builtin_amdgcn_mfma_f32_16x16x32_bf16(X0[rt][1], B0[0], a, 0, 0, 0);
            a = __builtin_amdgcn_mfma_f32_16x16x32_bf16(X0[rt][0], B0[1], a, 0, 0, 0);
            a = __builtin_amdgcn_mfma_f32_16x16x32_bf16(X1[rt][1], B1[0], a, 0, 0, 0);
            a = __builtin_amdgcn_mfma_f32_16x16x32_bf16(X1[rt][0], B1[1], a, 0, 0, 0);
            a = __builtin_amdgcn_mfma_f32_16x16x32_bf16(X0[rt][0], B0[0], a, 0, 0, 0);
            a = __builtin_amdgcn_mfma_f32_16x16x32_bf16(X1[rt][0], B1[0], a, 0, 0, 0);
            #pragma unroll
            for (int i = 0; i < 4; ++i) {
                float d = fmaf(-2.f, a[i], cnv);
                if (d < bd[rt][i]) { bd[rt][i] = d; bi[rt][i] = idxbase; }
            }
        }
    }

    if (half == 1) {
        #pragma unroll
        for (int rt = 0; rt < 4; ++rt)
            #pragma unroll
            for (int i = 0; i < 4; ++i) {
                sd[grp][l][rt * 4 + i] = bd[rt][i];
                si[grp][l][rt * 4 + i] = bi[rt][i];
            }
    }
    __syncthreads();
    if (half == 0) {
        float lm = 0.f;
        #pragma unroll
        for (int rt = 0; rt < 4; ++rt) {
            #pragma unroll
            for (int i = 0; i < 4; ++i) {
                float d = bd[rt][i]; int ix = bi[rt][i];
                float dp = sd[grp][l][rt * 4 + i];
                int   ip = si[grp][l][rt * 4 + i];
                if (dp < d || (dp == d && ip < ix)) { d = dp; ix = ip; }
                #pragma unroll
                for (int m = 1; m < 16; m <<= 1) {
                    float d2 = __shfl_xor(d, m, 64);
                    int   i2 = __shfl_xor(ix, m, 64);
                    if (d2 < d || (d2 == d && i2 < ix)) { d = d2; ix = i2; }
                }
                if (c16 == 0) {
                    size_t row = rowbase + rt * 16 + 4 * g + i;
                    out[2 * row + 1] = (float)(ix + KW);
                    lm += d + 1.0f;      // ||xf||^2 == 1
                }
            }
        }
        #pragma unroll
        for (int m = 1; m < 64; m <<= 1) lm += __shfl_xor(lm, m, 64);
        if (l == 0) red2[grp] = lm;
    }
    __syncthreads();
    if (tid == 0) atomicAdd(&sums[1], red2[0] + red2[1]);
}

// LDS histogram over the produced encodings -> global hist[1280].
__global__ __launch_bounds__(256) void hist_kernel(
    const float* __restrict__ out, int* __restrict__ hist)
{
    __shared__ int h[1280];
    const int tid = threadIdx.x;
    for (int i = tid; i < 1280; i += 256) h[i] = 0;
    __syncthreads();
    const int base = blockIdx.x * 1024;
    for (int rr = tid; rr < 1024; rr += 256) {
        const int r = base + rr;
        atomicAdd(&h[(int)out[2 * r]], 1);
        atomicAdd(&h[1024 + ((int)out[2 * r + 1] - KW)], 1);
    }
    __syncthreads();
    for (int i = tid; i < 1280; i += 256)
        if (h[i]) atomicAdd(&hist[i], h[i]);
}

__global__ __launch_bounds__(256) void finalize_kernel(
    const int* __restrict__ hist, const float* __restrict__ sums,
    float* __restrict__ out)
{
    __shared__ float red[4];
    const int tid = threadIdx.x;
    const bool wv = (blockIdx.x == 0);
    const int K = wv ? KW : KM;
    const int base = wv ? 0 : 1024;
    float s = 0.f;
    for (int i = tid; i < K; i += 256) {
        float p = (float)hist[base + i] * (1.0f / 65536.0f);
        s += p * logf(p + 1e-10f);
    }
    #pragma unroll
    for (int off = 32; off >= 1; off >>= 1) s += __shfl_xor(s, off, 64);
    if ((tid & 63) == 0) red[tid >> 6] = s;
    __syncthreads();
    if (tid == 0) {
        float t = red[0] + red[1] + red[2] + red[3];
        float ppl = expf(-t);
        float denom = wv ? (float)(NROWS * DW) : (float)(NROWS * DM);
        int obase = 2 * NROWS + (wv ? 0 : 2);
        out[obase]     = ppl;
        out[obase + 1] = 1.25f * sums[wv ? 0 : 1] / denom;
    }
}

extern "C" void kernel_launch(void* const* d_in, const int* in_sizes, int n_in,
                              void* d_out, int out_size, void* d_ws, size_t ws_size,
                              hipStream_t stream) {
    const float* X   = (const float*)d_in[0];
    const float* cbw = (const float*)d_in[1];
    const float* cbm = (const float*)d_in[2];
    float* out = (float*)d_out;

    char* ws = (char*)d_ws;
    float* sums = (float*)(ws + WS_SUMS);
    int*   hist = (int*)(ws + WS_HIST);
    float* cn_w = (float*)(ws + WS_CNW);
    float* cn_m = (float*)(ws + WS_CNM);
    short* ctf  = (short*)(ws + WS_CTF);
    short* cbf  = (short*)(ws + WS_CBF);
    short* cwh  = (short*)(ws + WS_CWH);
    short* cwl  = (short*)(ws + WS_CWL);

    prep_kernel<<<122, 256, 0, stream>>>(cbw, cbm, sums, hist, cn_w, cn_m,
                                         ctf, cbf, cwh, cwl);
    wave_vq_mfma<<<NROWS / 128, 256, 0, stream>>>(X, cwh, cwl, cn_w, out, sums);
    mfcc_mfma<<<NROWS / 128, 256, 0, stream>>>(X, cn_m, ctf, cbf, out, sums);
    hist_kernel<<<64, 256, 0, stream>>>(out, hist);
    finalize_kernel<<<2, 256, 0, stream>>>(hist, sums, out);
}